// Round 4
// baseline (475.477 us; speedup 1.0000x reference)
//
#include <hip/hip_runtime.h>

#define EPSF 1e-5f
#define C1 0.0625f

typedef short bf16x8 __attribute__((ext_vector_type(8)));
typedef short s16x4 __attribute__((ext_vector_type(4)));
typedef float f32x4 __attribute__((ext_vector_type(4)));
typedef unsigned short u16;

#define MFMA(a, b, c) __builtin_amdgcn_mfma_f32_16x16x32_bf16(a, b, c, 0, 0, 0)

__device__ __forceinline__ u16 f2bf(float x) {
  union { float f; unsigned u; } v; v.f = x;
  unsigned r = v.u + 0x7fffu + ((v.u >> 16) & 1u);   // round-to-nearest-even
  return (u16)(r >> 16);
}
__device__ __forceinline__ float bf2f(u16 h) {
  union { float f; unsigned u; } v; v.u = ((unsigned)h) << 16; return v.f;
}
__device__ __forceinline__ void split2(float x, u16& h, u16& l) {
  h = f2bf(x); l = f2bf(x - bf2f(h));
}
// swizzled index into a 64x64 u16 LDS tile: 16B granules XOR'd by row&7
__device__ __forceinline__ int XIDX(int r, int c) {
  return r * 64 + ((((c >> 3) ^ (r & 7)) << 3) | (c & 7));
}

// LDS overlay: cheb layers need C0h/C1h/Adj; econv needs Tf + sW.
struct ChebSh { u16 C0h[4096]; u16 C1h[4096]; u16 Adj[4096]; };
struct EcSh { float Tf[64 * 68]; unsigned sW[256]; };
union USh { ChebSh ch; EcSh ec; };

// ---------------------------------------------------------------------------
// global barrier: monotonic counters, fresh slot per use (zeroed by memset).
// 512 blocks = 8 groups x 64. Agent-scope fences around arrive/release.
// ---------------------------------------------------------------------------
__device__ __forceinline__ void gbarrier(unsigned* bar, int slot, int blk) {
  __syncthreads();
  if (threadIdx.x == 0) {
    __threadfence();
    unsigned* base = bar + slot * 160;
    unsigned old = atomicAdd(base + (blk & 7) * 16, 1u);
    if (old == 63u) atomicAdd(base + 128, 1u);
    while (__hip_atomic_load(base + 128, __ATOMIC_RELAXED,
                             __HIP_MEMORY_SCOPE_AGENT) < 8u)
      __builtin_amdgcn_s_sleep(2);
    __threadfence();
  }
  __syncthreads();
}

// Build local adjacency multiplicity matrix (bf16 exact ints <=16), wave 3.
__device__ __forceinline__ void build_adj(const int* __restrict__ src, int g,
                                          int r, u16* Adj) {
  bf16x8 z = {0, 0, 0, 0, 0, 0, 0, 0};
#pragma unroll
  for (int q = 0; q < 8; q++) *(bf16x8*)&Adj[r * 64 + q * 8] = z;
  const int4* s4 = (const int4*)(src + (size_t)g * 1024 + (size_t)r * 16);
  int4 a0 = s4[0], a1 = s4[1], a2 = s4[2], a3 = s4[3];
  int b0 = g * 64;
  int ss[16] = {a0.x - b0, a0.y - b0, a0.z - b0, a0.w - b0,
                a1.x - b0, a1.y - b0, a1.z - b0, a1.w - b0,
                a2.x - b0, a2.y - b0, a2.z - b0, a2.w - b0,
                a3.x - b0, a3.y - b0, a3.z - b0, a3.w - b0};
#pragma unroll
  for (int e = 0; e < 16; e++) {
    int idx = XIDX(r, ss[e]);
    Adj[idx] = f2bf(bf2f(Adj[idx]) + 1.0f);
  }
}

// load 8 fp32 weights, split to bf16 hi/lo frags
__device__ __forceinline__ void load_split8(const float* p, bf16x8& h, bf16x8& l) {
  float4 v0 = *(const float4*)p;
  float4 v1 = *(const float4*)(p + 4);
  float vv[8] = {v0.x, v0.y, v0.z, v0.w, v1.x, v1.y, v1.z, v1.w};
#pragma unroll
  for (int j = 0; j < 8; j++) {
    u16 hh, ll; split2(vv[j], hh, ll);
    h[j] = (short)hh; l[j] = (short)ll;
  }
}
__device__ __forceinline__ void load_split8_sub(const float* p, const float* q,
                                                bf16x8& h, bf16x8& l) {
  float4 v0 = *(const float4*)p;
  float4 v1 = *(const float4*)(p + 4);
  float4 u0 = *(const float4*)q;
  float4 u1 = *(const float4*)(q + 4);
  float vv[8] = {v0.x - u0.x, v0.y - u0.y, v0.z - u0.z, v0.w - u0.w,
                 v1.x - u1.x, v1.y - u1.y, v1.z - u1.z, v1.w - u1.w};
#pragma unroll
  for (int j = 0; j < 8; j++) {
    u16 hh, ll; split2(vv[j], hh, ll);
    h[j] = (short)hh; l[j] = (short)ll;
  }
}

__device__ __forceinline__ void bn_coeffs(const float* sStats, const float* gam,
                                          const float* bet, int c0, float* sc,
                                          float* sh) {
  const float inv = 1.0f / 65536.0f;
#pragma unroll
  for (int i = 0; i < 4; i++) {
    float m1 = sStats[c0 + i] * inv;
    float var = fmaf(sStats[64 + c0 + i], inv, -m1 * m1);
    float s = gam[c0 + i] * rsqrtf(var + EPSF);
    sc[i] = s;
    sh[i] = fmaf(-m1, s, bet[c0 + i]);
  }
}

// BN+ReLU the register-held pre-BN y, stage into NM (hi/lo) + optional CM(hi).
__device__ __forceinline__ void stage_from_regs(const f32x4* y,
                                                const float* sStats,
                                                const float* gam,
                                                const float* bet, int w, int ml,
                                                int kq, u16* NMh, u16* NMl,
                                                u16* CMh) {
  int c0 = w * 16 + kq * 4;
  float sc[4], sh[4];
  bn_coeffs(sStats, gam, bet, c0, sc, sh);
#pragma unroll
  for (int nt = 0; nt < 4; nt++) {
    int n = nt * 16 + ml;
    u16 hh[4], ll[4];
#pragma unroll
    for (int i = 0; i < 4; i++) {
      float h = fmaxf(fmaf(sc[i], y[nt][i], sh[i]), 0.f);
      split2(h, hh[i], ll[i]);
    }
    s16x4 vh, vl;
#pragma unroll
    for (int i = 0; i < 4; i++) { vh[i] = (short)hh[i]; vl[i] = (short)ll[i]; }
    *(s16x4*)&NMh[XIDX(n, c0)] = vh;
    *(s16x4*)&NMl[XIDX(n, c0)] = vl;
    if (CMh) {
#pragma unroll
      for (int i = 0; i < 4; i++) CMh[XIDX(c0 + i, n)] = (u16)hh[i];
    }
  }
}

// X_next = scale * Adj * X (X read ch-major hi-only); out -> NM (hi/lo) + opt CM
__device__ __forceinline__ void lap_step(const u16* Bh, const u16* Adj,
                                         float scale, int w, int ml, int kq,
                                         u16* NMh, u16* NMl, u16* oCh) {
  f32x4 l[4];
#pragma unroll
  for (int nt = 0; nt < 4; nt++) l[nt] = (f32x4){0.f, 0.f, 0.f, 0.f};
#pragma unroll
  for (int kt = 0; kt < 2; kt++) {
    int kk = kt * 32 + kq * 8;
    bf16x8 aa = *(const bf16x8*)&Adj[XIDX(w * 16 + ml, kk)];
#pragma unroll
    for (int nt = 0; nt < 4; nt++) {
      bf16x8 bh = *(const bf16x8*)&Bh[XIDX(nt * 16 + ml, kk)];
      l[nt] = MFMA(aa, bh, l[nt]);
    }
  }
  int r0 = w * 16 + kq * 4;
#pragma unroll
  for (int nt = 0; nt < 4; nt++) {
    int c = nt * 16 + ml;
    u16 hh[4], ll[4];
#pragma unroll
    for (int i = 0; i < 4; i++) {
      split2(l[nt][i] * scale, hh[i], ll[i]);
      NMh[XIDX(r0 + i, c)] = hh[i];
      NMl[XIDX(r0 + i, c)] = ll[i];
    }
    if (oCh) {
      s16x4 vh;
#pragma unroll
      for (int i = 0; i < 4; i++) vh[i] = (short)hh[i];
      *(s16x4*)&oCh[XIDX(c, r0)] = vh;
    }
  }
}

// acc += W[:, k0..k0+63] (fp32, split in-reg; optional fold subtrahend) @ X
__device__ __forceinline__ void yacc_k64(const float* wrow, const float* wfold,
                                         int w, int ml, int kq, const u16* NMh,
                                         const u16* NMl, f32x4* acc) {
#pragma unroll
  for (int kt = 0; kt < 2; kt++) {
    int c = kt * 32 + kq * 8;
    bf16x8 ah, al;
    if (wfold) load_split8_sub(wrow + c, wfold + c, ah, al);
    else load_split8(wrow + c, ah, al);
#pragma unroll
    for (int nt = 0; nt < 4; nt++) {
      bf16x8 bh = *(const bf16x8*)&NMh[XIDX(nt * 16 + ml, c)];
      bf16x8 bl = *(const bf16x8*)&NMl[XIDX(nt * 16 + ml, c)];
      acc[nt] = MFMA(ah, bh, acc[nt]);
      acc[nt] = MFMA(al, bh, acc[nt]);
      acc[nt] = MFMA(ah, bl, acc[nt]);
    }
  }
}

// ---------------------------------------------------------------------------
__global__ __launch_bounds__(256, 3) void k_fused(
    const float* __restrict__ feat, const int* __restrict__ src,
    const float* __restrict__ c1w, const float* __restrict__ c1b,
    const float* __restrict__ bn1g, const float* __restrict__ bn1b,
    const float* __restrict__ e1tw, const float* __restrict__ e1tb,
    const float* __restrict__ e1pw, const float* __restrict__ e1pb,
    const float* __restrict__ bne1g, const float* __restrict__ bne1b,
    const float* __restrict__ c2w, const float* __restrict__ c2b,
    const float* __restrict__ bn2g, const float* __restrict__ bn2b,
    const float* __restrict__ e2tw, const float* __restrict__ e2tb,
    const float* __restrict__ e2pw, const float* __restrict__ e2pb,
    const float* __restrict__ bne2g, const float* __restrict__ bne2b,
    const float* __restrict__ c3w, const float* __restrict__ c3b,
    const float* __restrict__ bn3g, const float* __restrict__ bn3b,
    float* __restrict__ out, float* __restrict__ part,
    float* __restrict__ gstats, unsigned* __restrict__ bar) {
  __shared__ __align__(16) u16 NMh[4096];
  __shared__ __align__(16) u16 NMl[4096];
  __shared__ __align__(16) USh U;
  __shared__ float sStats[128];
  __shared__ float sRed[256];

  const int t = threadIdx.x, blk = blockIdx.x;
  const int lane = t & 63;
  const int w = __builtin_amdgcn_readfirstlane(t >> 6);
  const int ml = lane & 15, kq = lane >> 4;
  const int c0 = w * 16 + kq * 4;
  float* prow = part + (size_t)blk * 128;

  f32x4 yA[4], yB[4];

  // ---- per-layer stats round: partials -> barrier -> reduce -> barrier ----
  auto stats_round = [&](int L) {
    float s1[4] = {0.f, 0.f, 0.f, 0.f}, s2[4] = {0.f, 0.f, 0.f, 0.f};
#pragma unroll
    for (int nt = 0; nt < 4; nt++) {
#pragma unroll
      for (int i = 0; i < 4; i++) {
        float a = yA[nt][i], b = yB[nt][i];
        s1[i] += a + b;
        s2[i] += a * a + b * b;
      }
    }
#pragma unroll
    for (int i = 0; i < 4; i++) {
#pragma unroll
      for (int off = 1; off < 16; off <<= 1) {
        s1[i] += __shfl_xor(s1[i], off, 64);
        s2[i] += __shfl_xor(s2[i], off, 64);
      }
    }
    if (ml == 0) {
      *(float4*)(prow + c0) = make_float4(s1[0], s1[1], s1[2], s1[3]);
      *(float4*)(prow + 64 + c0) = make_float4(s2[0], s2[1], s2[2], s2[3]);
    }
    gbarrier(bar, L * 2, blk);
    if (blk < 8) {
      int cc = t & 15, rg = t >> 4;
      const float* pp = part + (size_t)(rg * 32) * 128 + blk * 16 + cc;
      float a = 0.f;
#pragma unroll 8
      for (int r = 0; r < 32; r++) a += pp[(size_t)r * 128];
      sRed[t] = a;
      __syncthreads();
      if (t < 16) {
        float s = 0.f;
#pragma unroll
        for (int k = 0; k < 16; k++) s += sRed[k * 16 + t];
        gstats[L * 128 + blk * 16 + t] = s;
      }
    }
    gbarrier(bar, L * 2 + 1, blk);
    if (t < 128) sStats[t] = gstats[L * 128 + t];
    __syncthreads();
  };

  // ================= Layer 1: cheb1 (FIN=16, K padded to 64) ==============
  for (int gg = 0; gg < 2; gg++) {
    int g = blk * 2 + gg;
    f32x4* y = gg ? yB : yA;
    __syncthreads();
    {  // stage X0 = feat (node t>>2, ch (t&3)*4..+3); CM hi into U.ch.C0h
      int n = t >> 2, cc0 = (t & 3) * 4;
      float4 v = *(const float4*)(feat + (size_t)(g * 64 + n) * 16 + cc0);
      u16 hh[4], ll[4];
      split2(v.x, hh[0], ll[0]); split2(v.y, hh[1], ll[1]);
      split2(v.z, hh[2], ll[2]); split2(v.w, hh[3], ll[3]);
      s16x4 vh, vl;
#pragma unroll
      for (int i = 0; i < 4; i++) { vh[i] = (short)hh[i]; vl[i] = (short)ll[i]; }
      *(s16x4*)&NMh[XIDX(n, cc0)] = vh;
      *(s16x4*)&NMl[XIDX(n, cc0)] = vl;
#pragma unroll
      for (int i = 0; i < 4; i++) U.ch.C0h[XIDX(cc0 + i, n)] = (u16)hh[i];
    }
    if (w == 0) {
      bf16x8 z = {0, 0, 0, 0, 0, 0, 0, 0};
      *(bf16x8*)&NMh[XIDX(lane, 48)] = z;
      *(bf16x8*)&NMh[XIDX(lane, 56)] = z;
    } else if (w == 1) {
      bf16x8 z = {0, 0, 0, 0, 0, 0, 0, 0};
      *(bf16x8*)&NMl[XIDX(lane, 48)] = z;
      *(bf16x8*)&NMl[XIDX(lane, 56)] = z;
    } else if (w == 3) {
      build_adj(src, g, lane, U.ch.Adj);
    }
    __syncthreads();
    {  // lap1: X1 (chs 0..15) -> NM cols 16..31 (hi/lo) + CM rows 16..31 (hi)
      f32x4 l = {0.f, 0.f, 0.f, 0.f};
#pragma unroll
      for (int kt = 0; kt < 2; kt++) {
        int kk = kt * 32 + kq * 8;
        bf16x8 aa = *(const bf16x8*)&U.ch.Adj[XIDX(w * 16 + ml, kk)];
        bf16x8 bh = *(const bf16x8*)&U.ch.C0h[XIDX(ml, kk)];
        l = MFMA(aa, bh, l);
      }
      int r0 = w * 16 + kq * 4;
      u16 hh[4], ll[4];
#pragma unroll
      for (int i = 0; i < 4; i++) {
        split2(l[i] * (-C1), hh[i], ll[i]);
        NMh[XIDX(r0 + i, 16 + ml)] = hh[i];
        NMl[XIDX(r0 + i, 16 + ml)] = ll[i];
      }
      s16x4 vh;
#pragma unroll
      for (int i = 0; i < 4; i++) vh[i] = (short)hh[i];
      *(s16x4*)&U.ch.C0h[XIDX(16 + ml, r0)] = vh;
    }
    __syncthreads();
    {  // lap2: Z2 = -2C1*Adj*X1 -> NM cols 32..47
      f32x4 l = {0.f, 0.f, 0.f, 0.f};
#pragma unroll
      for (int kt = 0; kt < 2; kt++) {
        int kk = kt * 32 + kq * 8;
        bf16x8 aa = *(const bf16x8*)&U.ch.Adj[XIDX(w * 16 + ml, kk)];
        bf16x8 bh = *(const bf16x8*)&U.ch.C0h[XIDX(16 + ml, kk)];
        l = MFMA(aa, bh, l);
      }
      int r0 = w * 16 + kq * 4;
#pragma unroll
      for (int i = 0; i < 4; i++) {
        u16 hh, ll;
        split2(l[i] * (-2.0f * C1), hh, ll);
        NMh[XIDX(r0 + i, 32 + ml)] = hh;
        NMl[XIDX(r0 + i, 32 + ml)] = ll;
      }
    }
    __syncthreads();
    {  // Y = Xcat @ Wfold^T (K=64, regioned fp32 W with in-reg fold/split)
      f32x4 acc[4];
#pragma unroll
      for (int nt = 0; nt < 4; nt++) acc[nt] = (f32x4){0.f, 0.f, 0.f, 0.f};
      const float* wr = c1w + (size_t)(w * 16 + ml) * 48;
#pragma unroll
      for (int kt = 0; kt < 2; kt++) {
        int c = kt * 32 + kq * 8;
        float vv[8];
        if (c < 16) {
          float4 a0 = *(const float4*)(wr + c), a1 = *(const float4*)(wr + c + 4);
          float4 b0 = *(const float4*)(wr + 32 + c),
                 b1 = *(const float4*)(wr + 32 + c + 4);
          vv[0] = a0.x - b0.x; vv[1] = a0.y - b0.y; vv[2] = a0.z - b0.z;
          vv[3] = a0.w - b0.w; vv[4] = a1.x - b1.x; vv[5] = a1.y - b1.y;
          vv[6] = a1.z - b1.z; vv[7] = a1.w - b1.w;
        } else if (c < 48) {
          float4 a0 = *(const float4*)(wr + c), a1 = *(const float4*)(wr + c + 4);
          vv[0] = a0.x; vv[1] = a0.y; vv[2] = a0.z; vv[3] = a0.w;
          vv[4] = a1.x; vv[5] = a1.y; vv[6] = a1.z; vv[7] = a1.w;
        } else {
#pragma unroll
          for (int j = 0; j < 8; j++) vv[j] = 0.f;
        }
        bf16x8 ah, al;
#pragma unroll
        for (int j = 0; j < 8; j++) {
          u16 hh, ll; split2(vv[j], hh, ll);
          ah[j] = (short)hh; al[j] = (short)ll;
        }
#pragma unroll
        for (int nt = 0; nt < 4; nt++) {
          bf16x8 bh = *(const bf16x8*)&NMh[XIDX(nt * 16 + ml, c)];
          bf16x8 bl = *(const bf16x8*)&NMl[XIDX(nt * 16 + ml, c)];
          acc[nt] = MFMA(ah, bh, acc[nt]);
          acc[nt] = MFMA(al, bh, acc[nt]);
          acc[nt] = MFMA(ah, bl, acc[nt]);
        }
      }
      float4 bb = *(const float4*)(c1b + c0);
#pragma unroll
      for (int nt = 0; nt < 4; nt++) {
        y[nt][0] = acc[nt][0] + bb.x; y[nt][1] = acc[nt][1] + bb.y;
        y[nt][2] = acc[nt][2] + bb.z; y[nt][3] = acc[nt][3] + bb.w;
      }
    }
  }
  stats_round(0);

  // ================= econv layers (2 and 4) ===============================
  auto econv_layer = [&](const float* gam, const float* bet, const float* tw,
                         const float* tb, const float* pw, const float* pb) {
    for (int gg = 0; gg < 2; gg++) {
      int g = blk * 2 + gg;
      f32x4* y = gg ? yB : yA;
      __syncthreads();
      stage_from_regs(y, sStats, gam, bet, w, ml, kq, NMh, NMl, nullptr);
      {
        int4 v = ((const int4*)(src + (size_t)g * 1024))[t];
        int b0 = g * 64;
        U.ec.sW[t] = (unsigned)(v.x - b0) | ((unsigned)(v.y - b0) << 8) |
                     ((unsigned)(v.z - b0) << 16) | ((unsigned)(v.w - b0) << 24);
      }
      __syncthreads();
      f32x4 T[4], P[4];
#pragma unroll
      for (int nt = 0; nt < 4; nt++) {
        T[nt] = (f32x4){0.f, 0.f, 0.f, 0.f};
        P[nt] = (f32x4){0.f, 0.f, 0.f, 0.f};
      }
      const float* twr = tw + (size_t)(w * 16 + ml) * 64;
      const float* pwr = pw + (size_t)(w * 16 + ml) * 64;
#pragma unroll
      for (int kt = 0; kt < 2; kt++) {
        int c = kt * 32 + kq * 8;
        bf16x8 ath, atl, aph, apl;
        load_split8(twr + c, ath, atl);
        load_split8(pwr + c, aph, apl);
#pragma unroll
        for (int nt = 0; nt < 4; nt++) {
          bf16x8 bh = *(const bf16x8*)&NMh[XIDX(nt * 16 + ml, c)];
          bf16x8 bl = *(const bf16x8*)&NMl[XIDX(nt * 16 + ml, c)];
          T[nt] = MFMA(ath, bh, T[nt]); T[nt] = MFMA(atl, bh, T[nt]);
          T[nt] = MFMA(ath, bl, T[nt]);
          P[nt] = MFMA(aph, bh, P[nt]); P[nt] = MFMA(apl, bh, P[nt]);
          P[nt] = MFMA(aph, bl, P[nt]);
        }
      }
#pragma unroll
      for (int nt = 0; nt < 4; nt++) {
        int n = nt * 16 + ml;
        *(float4*)&U.ec.Tf[n * 68 + c0] =
            make_float4(T[nt][0], T[nt][1], T[nt][2], T[nt][3]);
      }
      float4 tbv = *(const float4*)(tb + c0);
      float4 pbv = *(const float4*)(pb + c0);
#pragma unroll
      for (int nt = 0; nt < 4; nt++) {
        int n = nt * 16 + ml;
        unsigned w0 = U.ec.sW[n * 4], w1 = U.ec.sW[n * 4 + 1],
                 w2v = U.ec.sW[n * 4 + 2], w3v = U.ec.sW[n * 4 + 3];
        float4 mn = {3.4e38f, 3.4e38f, 3.4e38f, 3.4e38f};
#pragma unroll
        for (int e = 0; e < 16; e++) {
          unsigned wd = (e < 4) ? w0 : (e < 8) ? w1 : (e < 12) ? w2v : w3v;
          int s = (wd >> ((e & 3) * 8)) & 255;
          float4 tv = *(const float4*)&U.ec.Tf[s * 68 + c0];
          mn.x = fminf(mn.x, tv.x); mn.y = fminf(mn.y, tv.y);
          mn.z = fminf(mn.z, tv.z); mn.w = fminf(mn.w, tv.w);
        }
        y[nt][0] = T[nt][0] + P[nt][0] + tbv.x + pbv.x - mn.x;
        y[nt][1] = T[nt][1] + P[nt][1] + tbv.y + pbv.y - mn.y;
        y[nt][2] = T[nt][2] + P[nt][2] + tbv.z + pbv.z - mn.z;
        y[nt][3] = T[nt][3] + P[nt][3] + tbv.w + pbv.w - mn.w;
      }
    }
  };

  // ================= cheb64 layers (3 and 5) ==============================
  auto cheb64_layer = [&](const float* gam, const float* bet, const float* W,
                          const float* bias) {
    for (int gg = 0; gg < 2; gg++) {
      int g = blk * 2 + gg;
      f32x4* y = gg ? yB : yA;
      __syncthreads();
      stage_from_regs(y, sStats, gam, bet, w, ml, kq, NMh, NMl, U.ch.C0h);
      if (w == 3) build_adj(src, g, lane, U.ch.Adj);
      __syncthreads();
      f32x4 acc[4];
#pragma unroll
      for (int nt = 0; nt < 4; nt++) acc[nt] = (f32x4){0.f, 0.f, 0.f, 0.f};
      const float* wr = W + (size_t)(w * 16 + ml) * 192;
      yacc_k64(wr, wr + 128, w, ml, kq, NMh, NMl, acc);  // W0-W2 fold @ X0
      __syncthreads();
      lap_step(U.ch.C0h, U.ch.Adj, -C1, w, ml, kq, NMh, NMl, U.ch.C1h);
      __syncthreads();
      yacc_k64(wr + 64, nullptr, w, ml, kq, NMh, NMl, acc);  // W1 @ X1
      __syncthreads();
      lap_step(U.ch.C1h, U.ch.Adj, -2.0f * C1, w, ml, kq, NMh, NMl, nullptr);
      __syncthreads();
      yacc_k64(wr + 128, nullptr, w, ml, kq, NMh, NMl, acc);  // W2 @ Z2
      float4 bb = *(const float4*)(bias + c0);
#pragma unroll
      for (int nt = 0; nt < 4; nt++) {
        y[nt][0] = acc[nt][0] + bb.x; y[nt][1] = acc[nt][1] + bb.y;
        y[nt][2] = acc[nt][2] + bb.z; y[nt][3] = acc[nt][3] + bb.w;
      }
    }
  };

  econv_layer(bn1g, bn1b, e1tw, e1tb, e1pw, e1pb);
  stats_round(1);
  cheb64_layer(bne1g, bne1b, c2w, c2b);
  stats_round(2);
  econv_layer(bn2g, bn2b, e2tw, e2tb, e2pw, e2pb);
  stats_round(3);
  cheb64_layer(bne2g, bne2b, c3w, c3b);
  stats_round(4);

  // ================= final BN+ReLU + mean pool ============================
  for (int gg = 0; gg < 2; gg++) {
    int g = blk * 2 + gg;
    f32x4* y = gg ? yB : yA;
    float sc[4], sh[4];
    bn_coeffs(sStats, bn3g, bn3b, c0, sc, sh);
    float vs[4] = {0.f, 0.f, 0.f, 0.f};
#pragma unroll
    for (int nt = 0; nt < 4; nt++)
#pragma unroll
      for (int i = 0; i < 4; i++)
        vs[i] += fmaxf(fmaf(sc[i], y[nt][i], sh[i]), 0.f);
#pragma unroll
    for (int i = 0; i < 4; i++)
#pragma unroll
      for (int off = 1; off < 16; off <<= 1) vs[i] += __shfl_xor(vs[i], off, 64);
    if (ml == 0) {
      const float r64 = 1.0f / 64.0f;
      *(float4*)(out + (size_t)g * 64 + c0) =
          make_float4(vs[0] * r64, vs[1] * r64, vs[2] * r64, vs[3] * r64);
    }
  }
}

// ---------------------------------------------------------------------------
extern "C" void kernel_launch(void* const* d_in, const int* in_sizes, int n_in,
                              void* d_out, int out_size, void* d_ws,
                              size_t ws_size, hipStream_t stream) {
  const float* feat = (const float*)d_in[0];
  const int* src = (const int*)d_in[1];
  const float* cheb1_w = (const float*)d_in[4];
  const float* cheb1_b = (const float*)d_in[5];
  const float* bn1_g = (const float*)d_in[6];
  const float* bn1_b = (const float*)d_in[7];
  const float* e1_tw = (const float*)d_in[8];
  const float* e1_tb = (const float*)d_in[9];
  const float* e1_pw = (const float*)d_in[10];
  const float* e1_pb = (const float*)d_in[11];
  const float* bne1_g = (const float*)d_in[12];
  const float* bne1_b = (const float*)d_in[13];
  const float* cheb2_w = (const float*)d_in[14];
  const float* cheb2_b = (const float*)d_in[15];
  const float* bn2_g = (const float*)d_in[16];
  const float* bn2_b = (const float*)d_in[17];
  const float* e2_tw = (const float*)d_in[18];
  const float* e2_tb = (const float*)d_in[19];
  const float* e2_pw = (const float*)d_in[20];
  const float* e2_pb = (const float*)d_in[21];
  const float* bne2_g = (const float*)d_in[22];
  const float* bne2_b = (const float*)d_in[23];
  const float* cheb3_w = (const float*)d_in[24];
  const float* cheb3_b = (const float*)d_in[25];
  const float* bn3_g = (const float*)d_in[26];
  const float* bn3_b = (const float*)d_in[27];

  float* part = (float*)d_ws;                       // 512 x 128
  float* gstats = part + 512 * 128;                 // 5 x 128
  unsigned* bar = (unsigned*)(gstats + 5 * 128);    // 10 slots x 640 B

  hipMemsetAsync(bar, 0, 8192, stream);

  k_fused<<<512, 256, 0, stream>>>(
      feat, src, cheb1_w, cheb1_b, bn1_g, bn1_b, e1_tw, e1_tb, e1_pw, e1_pb,
      bne1_g, bne1_b, cheb2_w, cheb2_b, bn2_g, bn2_b, e2_tw, e2_tb, e2_pw,
      e2_pb, bne2_g, bne2_b, cheb3_w, cheb3_b, bn3_g, bn3_b, (float*)d_out,
      part, gstats, bar);
}

// Round 5
// 304.986 us; speedup vs baseline: 1.5590x; 1.5590x over previous
//
#include <hip/hip_runtime.h>

#define EPSF 1e-5f
#define C1 0.0625f

typedef short bf16x8 __attribute__((ext_vector_type(8)));
typedef short s16x4 __attribute__((ext_vector_type(4)));
typedef float f32x4 __attribute__((ext_vector_type(4)));
typedef unsigned short u16;

#define MFMA(a, b, c) __builtin_amdgcn_mfma_f32_16x16x32_bf16(a, b, c, 0, 0, 0)

// coherent (cross-XCD) scalar access helpers — lower to global_* with sc1,
// touching ONLY these addresses (no cache-wide invalidate/writeback).
__device__ __forceinline__ void cstore(float* p, float v) {
  __hip_atomic_store(p, v, __ATOMIC_RELAXED, __HIP_MEMORY_SCOPE_AGENT);
}
__device__ __forceinline__ float cload(const float* p) {
  return __hip_atomic_load(p, __ATOMIC_RELAXED, __HIP_MEMORY_SCOPE_AGENT);
}

__device__ __forceinline__ u16 f2bf(float x) {
  union { float f; unsigned u; } v; v.f = x;
  unsigned r = v.u + 0x7fffu + ((v.u >> 16) & 1u);   // round-to-nearest-even
  return (u16)(r >> 16);
}
__device__ __forceinline__ float bf2f(u16 h) {
  union { float f; unsigned u; } v; v.u = ((unsigned)h) << 16; return v.f;
}
__device__ __forceinline__ void split2(float x, u16& h, u16& l) {
  h = f2bf(x); l = f2bf(x - bf2f(h));
}
// swizzled index into a 64x64 u16 LDS tile: 16B granules XOR'd by row&7
__device__ __forceinline__ int XIDX(int r, int c) {
  return r * 64 + ((((c >> 3) ^ (r & 7)) << 3) | (c & 7));
}

// LDS overlay: cheb layers need C0h/C1h/Adj; econv needs Tf + sW.
struct ChebSh { u16 C0h[4096]; u16 C1h[4096]; u16 Adj[4096]; };
struct EcSh { float Tf[64 * 68]; unsigned sW[256]; };
union USh { ChebSh ch; EcSh ec; };

// ---------------------------------------------------------------------------
// global barrier: monotonic counters, fresh slot per use (zeroed by memset).
// 512 blocks = 8 groups x 64. NO fences: data moves via coherent (sc1)
// atomics; __syncthreads' pre-barrier vmcnt drain + s_waitcnt(0) give order.
// ---------------------------------------------------------------------------
__device__ __forceinline__ void gbarrier(unsigned* bar, int slot, int blk) {
  __syncthreads();   // compiler drains vmcnt(0) before s_barrier
  if (threadIdx.x == 0) {
    __builtin_amdgcn_s_waitcnt(0);   // belt-and-braces: all our vmem acked
    unsigned* base = bar + slot * 160;
    unsigned old = atomicAdd(base + (blk & 7) * 16, 1u);
    if (old == 63u) atomicAdd(base + 128, 1u);
    while (__hip_atomic_load(base + 128, __ATOMIC_RELAXED,
                             __HIP_MEMORY_SCOPE_AGENT) < 8u)
      __builtin_amdgcn_s_sleep(4);
  }
  __syncthreads();
}

// Build local adjacency multiplicity matrix (bf16 exact ints <=16), wave 3.
__device__ __forceinline__ void build_adj(const int* __restrict__ src, int g,
                                          int r, u16* Adj) {
  bf16x8 z = {0, 0, 0, 0, 0, 0, 0, 0};
#pragma unroll
  for (int q = 0; q < 8; q++) *(bf16x8*)&Adj[r * 64 + q * 8] = z;
  const int4* s4 = (const int4*)(src + (size_t)g * 1024 + (size_t)r * 16);
  int4 a0 = s4[0], a1 = s4[1], a2 = s4[2], a3 = s4[3];
  int b0 = g * 64;
  int ss[16] = {a0.x - b0, a0.y - b0, a0.z - b0, a0.w - b0,
                a1.x - b0, a1.y - b0, a1.z - b0, a1.w - b0,
                a2.x - b0, a2.y - b0, a2.z - b0, a2.w - b0,
                a3.x - b0, a3.y - b0, a3.z - b0, a3.w - b0};
#pragma unroll
  for (int e = 0; e < 16; e++) {
    int idx = XIDX(r, ss[e]);
    Adj[idx] = f2bf(bf2f(Adj[idx]) + 1.0f);
  }
}

// load 8 fp32 weights, split to bf16 hi/lo frags
__device__ __forceinline__ void load_split8(const float* p, bf16x8& h, bf16x8& l) {
  float4 v0 = *(const float4*)p;
  float4 v1 = *(const float4*)(p + 4);
  float vv[8] = {v0.x, v0.y, v0.z, v0.w, v1.x, v1.y, v1.z, v1.w};
#pragma unroll
  for (int j = 0; j < 8; j++) {
    u16 hh, ll; split2(vv[j], hh, ll);
    h[j] = (short)hh; l[j] = (short)ll;
  }
}
__device__ __forceinline__ void load_split8_sub(const float* p, const float* q,
                                                bf16x8& h, bf16x8& l) {
  float4 v0 = *(const float4*)p;
  float4 v1 = *(const float4*)(p + 4);
  float4 u0 = *(const float4*)q;
  float4 u1 = *(const float4*)(q + 4);
  float vv[8] = {v0.x - u0.x, v0.y - u0.y, v0.z - u0.z, v0.w - u0.w,
                 v1.x - u1.x, v1.y - u1.y, v1.z - u1.z, v1.w - u1.w};
#pragma unroll
  for (int j = 0; j < 8; j++) {
    u16 hh, ll; split2(vv[j], hh, ll);
    h[j] = (short)hh; l[j] = (short)ll;
  }
}

__device__ __forceinline__ void bn_coeffs(const float* sStats, const float* gam,
                                          const float* bet, int c0, float* sc,
                                          float* sh) {
  const float inv = 1.0f / 65536.0f;
#pragma unroll
  for (int i = 0; i < 4; i++) {
    float m1 = sStats[c0 + i] * inv;
    float var = fmaf(sStats[64 + c0 + i], inv, -m1 * m1);
    float s = gam[c0 + i] * rsqrtf(var + EPSF);
    sc[i] = s;
    sh[i] = fmaf(-m1, s, bet[c0 + i]);
  }
}

// BN+ReLU the register-held pre-BN y, stage into NM (hi/lo) + optional CM(hi).
__device__ __forceinline__ void stage_from_regs(const f32x4* y,
                                                const float* sStats,
                                                const float* gam,
                                                const float* bet, int w, int ml,
                                                int kq, u16* NMh, u16* NMl,
                                                u16* CMh) {
  int c0 = w * 16 + kq * 4;
  float sc[4], sh[4];
  bn_coeffs(sStats, gam, bet, c0, sc, sh);
#pragma unroll
  for (int nt = 0; nt < 4; nt++) {
    int n = nt * 16 + ml;
    u16 hh[4], ll[4];
#pragma unroll
    for (int i = 0; i < 4; i++) {
      float h = fmaxf(fmaf(sc[i], y[nt][i], sh[i]), 0.f);
      split2(h, hh[i], ll[i]);
    }
    s16x4 vh, vl;
#pragma unroll
    for (int i = 0; i < 4; i++) { vh[i] = (short)hh[i]; vl[i] = (short)ll[i]; }
    *(s16x4*)&NMh[XIDX(n, c0)] = vh;
    *(s16x4*)&NMl[XIDX(n, c0)] = vl;
    if (CMh) {
#pragma unroll
      for (int i = 0; i < 4; i++) CMh[XIDX(c0 + i, n)] = (u16)hh[i];
    }
  }
}

// X_next = scale * Adj * X (X read ch-major hi-only); out -> NM (hi/lo) + opt CM
__device__ __forceinline__ void lap_step(const u16* Bh, const u16* Adj,
                                         float scale, int w, int ml, int kq,
                                         u16* NMh, u16* NMl, u16* oCh) {
  f32x4 l[4];
#pragma unroll
  for (int nt = 0; nt < 4; nt++) l[nt] = (f32x4){0.f, 0.f, 0.f, 0.f};
#pragma unroll
  for (int kt = 0; kt < 2; kt++) {
    int kk = kt * 32 + kq * 8;
    bf16x8 aa = *(const bf16x8*)&Adj[XIDX(w * 16 + ml, kk)];
#pragma unroll
    for (int nt = 0; nt < 4; nt++) {
      bf16x8 bh = *(const bf16x8*)&Bh[XIDX(nt * 16 + ml, kk)];
      l[nt] = MFMA(aa, bh, l[nt]);
    }
  }
  int r0 = w * 16 + kq * 4;
#pragma unroll
  for (int nt = 0; nt < 4; nt++) {
    int c = nt * 16 + ml;
    u16 hh[4], ll[4];
#pragma unroll
    for (int i = 0; i < 4; i++) {
      split2(l[nt][i] * scale, hh[i], ll[i]);
      NMh[XIDX(r0 + i, c)] = hh[i];
      NMl[XIDX(r0 + i, c)] = ll[i];
    }
    if (oCh) {
      s16x4 vh;
#pragma unroll
      for (int i = 0; i < 4; i++) vh[i] = (short)hh[i];
      *(s16x4*)&oCh[XIDX(c, r0)] = vh;
    }
  }
}

// acc += W[:, k0..k0+63] (fp32, split in-reg; optional fold subtrahend) @ X
__device__ __forceinline__ void yacc_k64(const float* wrow, const float* wfold,
                                         int w, int ml, int kq, const u16* NMh,
                                         const u16* NMl, f32x4* acc) {
#pragma unroll
  for (int kt = 0; kt < 2; kt++) {
    int c = kt * 32 + kq * 8;
    bf16x8 ah, al;
    if (wfold) load_split8_sub(wrow + c, wfold + c, ah, al);
    else load_split8(wrow + c, ah, al);
#pragma unroll
    for (int nt = 0; nt < 4; nt++) {
      bf16x8 bh = *(const bf16x8*)&NMh[XIDX(nt * 16 + ml, c)];
      bf16x8 bl = *(const bf16x8*)&NMl[XIDX(nt * 16 + ml, c)];
      acc[nt] = MFMA(ah, bh, acc[nt]);
      acc[nt] = MFMA(al, bh, acc[nt]);
      acc[nt] = MFMA(ah, bl, acc[nt]);
    }
  }
}

// ---------------------------------------------------------------------------
__global__ __launch_bounds__(256, 3) void k_fused(
    const float* __restrict__ feat, const int* __restrict__ src,
    const float* __restrict__ c1w, const float* __restrict__ c1b,
    const float* __restrict__ bn1g, const float* __restrict__ bn1b,
    const float* __restrict__ e1tw, const float* __restrict__ e1tb,
    const float* __restrict__ e1pw, const float* __restrict__ e1pb,
    const float* __restrict__ bne1g, const float* __restrict__ bne1b,
    const float* __restrict__ c2w, const float* __restrict__ c2b,
    const float* __restrict__ bn2g, const float* __restrict__ bn2b,
    const float* __restrict__ e2tw, const float* __restrict__ e2tb,
    const float* __restrict__ e2pw, const float* __restrict__ e2pb,
    const float* __restrict__ bne2g, const float* __restrict__ bne2b,
    const float* __restrict__ c3w, const float* __restrict__ c3b,
    const float* __restrict__ bn3g, const float* __restrict__ bn3b,
    float* __restrict__ out, float* __restrict__ part,
    float* __restrict__ gstats, unsigned* __restrict__ bar) {
  __shared__ __align__(16) u16 NMh[4096];
  __shared__ __align__(16) u16 NMl[4096];
  __shared__ __align__(16) USh U;
  __shared__ float sStats[128];
  __shared__ float sRed[256];

  const int t = threadIdx.x, blk = blockIdx.x;
  const int lane = t & 63;
  const int w = __builtin_amdgcn_readfirstlane(t >> 6);
  const int ml = lane & 15, kq = lane >> 4;
  const int c0 = w * 16 + kq * 4;
  float* prow = part + (size_t)blk * 128;

  f32x4 yA[4], yB[4];

  // ---- per-layer stats round: partials -> barrier -> reduce -> barrier ----
  auto stats_round = [&](int L) {
    float s1[4] = {0.f, 0.f, 0.f, 0.f}, s2[4] = {0.f, 0.f, 0.f, 0.f};
#pragma unroll
    for (int nt = 0; nt < 4; nt++) {
#pragma unroll
      for (int i = 0; i < 4; i++) {
        float a = yA[nt][i], b = yB[nt][i];
        s1[i] += a + b;
        s2[i] += a * a + b * b;
      }
    }
#pragma unroll
    for (int i = 0; i < 4; i++) {
#pragma unroll
      for (int off = 1; off < 16; off <<= 1) {
        s1[i] += __shfl_xor(s1[i], off, 64);
        s2[i] += __shfl_xor(s2[i], off, 64);
      }
    }
    if (ml == 0) {
#pragma unroll
      for (int i = 0; i < 4; i++) {
        cstore(prow + c0 + i, s1[i]);
        cstore(prow + 64 + c0 + i, s2[i]);
      }
    }
    gbarrier(bar, L * 2, blk);
    if (blk < 8) {
      int cc = t & 15, rg = t >> 4;
      const float* pp = part + (size_t)(rg * 32) * 128 + blk * 16 + cc;
      float a = 0.f;
#pragma unroll 8
      for (int r = 0; r < 32; r++) a += cload(pp + (size_t)r * 128);
      sRed[t] = a;
      __syncthreads();
      if (t < 16) {
        float s = 0.f;
#pragma unroll
        for (int k = 0; k < 16; k++) s += sRed[k * 16 + t];
        cstore(gstats + L * 128 + blk * 16 + t, s);
      }
    }
    gbarrier(bar, L * 2 + 1, blk);
    if (t < 128) sStats[t] = cload(gstats + L * 128 + t);
    __syncthreads();
  };

  // ================= Layer 1: cheb1 (FIN=16, K padded to 64) ==============
  for (int gg = 0; gg < 2; gg++) {
    int g = blk * 2 + gg;
    f32x4* y = gg ? yB : yA;
    __syncthreads();
    {  // stage X0 = feat (node t>>2, ch (t&3)*4..+3); CM hi into U.ch.C0h
      int n = t >> 2, cc0 = (t & 3) * 4;
      float4 v = *(const float4*)(feat + (size_t)(g * 64 + n) * 16 + cc0);
      u16 hh[4], ll[4];
      split2(v.x, hh[0], ll[0]); split2(v.y, hh[1], ll[1]);
      split2(v.z, hh[2], ll[2]); split2(v.w, hh[3], ll[3]);
      s16x4 vh, vl;
#pragma unroll
      for (int i = 0; i < 4; i++) { vh[i] = (short)hh[i]; vl[i] = (short)ll[i]; }
      *(s16x4*)&NMh[XIDX(n, cc0)] = vh;
      *(s16x4*)&NMl[XIDX(n, cc0)] = vl;
#pragma unroll
      for (int i = 0; i < 4; i++) U.ch.C0h[XIDX(cc0 + i, n)] = (u16)hh[i];
    }
    if (w == 0) {
      bf16x8 z = {0, 0, 0, 0, 0, 0, 0, 0};
      *(bf16x8*)&NMh[XIDX(lane, 48)] = z;
      *(bf16x8*)&NMh[XIDX(lane, 56)] = z;
    } else if (w == 1) {
      bf16x8 z = {0, 0, 0, 0, 0, 0, 0, 0};
      *(bf16x8*)&NMl[XIDX(lane, 48)] = z;
      *(bf16x8*)&NMl[XIDX(lane, 56)] = z;
    } else if (w == 3) {
      build_adj(src, g, lane, U.ch.Adj);
    }
    __syncthreads();
    {  // lap1: X1 (chs 0..15) -> NM cols 16..31 (hi/lo) + CM rows 16..31 (hi)
      f32x4 l = {0.f, 0.f, 0.f, 0.f};
#pragma unroll
      for (int kt = 0; kt < 2; kt++) {
        int kk = kt * 32 + kq * 8;
        bf16x8 aa = *(const bf16x8*)&U.ch.Adj[XIDX(w * 16 + ml, kk)];
        bf16x8 bh = *(const bf16x8*)&U.ch.C0h[XIDX(ml, kk)];
        l = MFMA(aa, bh, l);
      }
      int r0 = w * 16 + kq * 4;
      u16 hh[4], ll[4];
#pragma unroll
      for (int i = 0; i < 4; i++) {
        split2(l[i] * (-C1), hh[i], ll[i]);
        NMh[XIDX(r0 + i, 16 + ml)] = hh[i];
        NMl[XIDX(r0 + i, 16 + ml)] = ll[i];
      }
      s16x4 vh;
#pragma unroll
      for (int i = 0; i < 4; i++) vh[i] = (short)hh[i];
      *(s16x4*)&U.ch.C0h[XIDX(16 + ml, r0)] = vh;
    }
    __syncthreads();
    {  // lap2: Z2 = -2C1*Adj*X1 -> NM cols 32..47
      f32x4 l = {0.f, 0.f, 0.f, 0.f};
#pragma unroll
      for (int kt = 0; kt < 2; kt++) {
        int kk = kt * 32 + kq * 8;
        bf16x8 aa = *(const bf16x8*)&U.ch.Adj[XIDX(w * 16 + ml, kk)];
        bf16x8 bh = *(const bf16x8*)&U.ch.C0h[XIDX(16 + ml, kk)];
        l = MFMA(aa, bh, l);
      }
      int r0 = w * 16 + kq * 4;
#pragma unroll
      for (int i = 0; i < 4; i++) {
        u16 hh, ll;
        split2(l[i] * (-2.0f * C1), hh, ll);
        NMh[XIDX(r0 + i, 32 + ml)] = hh;
        NMl[XIDX(r0 + i, 32 + ml)] = ll;
      }
    }
    __syncthreads();
    {  // Y = Xcat @ Wfold^T (K=64, regioned fp32 W with in-reg fold/split)
      f32x4 acc[4];
#pragma unroll
      for (int nt = 0; nt < 4; nt++) acc[nt] = (f32x4){0.f, 0.f, 0.f, 0.f};
      const float* wr = c1w + (size_t)(w * 16 + ml) * 48;
#pragma unroll
      for (int kt = 0; kt < 2; kt++) {
        int c = kt * 32 + kq * 8;
        float vv[8];
        if (c < 16) {
          float4 a0 = *(const float4*)(wr + c), a1 = *(const float4*)(wr + c + 4);
          float4 b0 = *(const float4*)(wr + 32 + c),
                 b1 = *(const float4*)(wr + 32 + c + 4);
          vv[0] = a0.x - b0.x; vv[1] = a0.y - b0.y; vv[2] = a0.z - b0.z;
          vv[3] = a0.w - b0.w; vv[4] = a1.x - b1.x; vv[5] = a1.y - b1.y;
          vv[6] = a1.z - b1.z; vv[7] = a1.w - b1.w;
        } else if (c < 48) {
          float4 a0 = *(const float4*)(wr + c), a1 = *(const float4*)(wr + c + 4);
          vv[0] = a0.x; vv[1] = a0.y; vv[2] = a0.z; vv[3] = a0.w;
          vv[4] = a1.x; vv[5] = a1.y; vv[6] = a1.z; vv[7] = a1.w;
        } else {
#pragma unroll
          for (int j = 0; j < 8; j++) vv[j] = 0.f;
        }
        bf16x8 ah, al;
#pragma unroll
        for (int j = 0; j < 8; j++) {
          u16 hh, ll; split2(vv[j], hh, ll);
          ah[j] = (short)hh; al[j] = (short)ll;
        }
#pragma unroll
        for (int nt = 0; nt < 4; nt++) {
          bf16x8 bh = *(const bf16x8*)&NMh[XIDX(nt * 16 + ml, c)];
          bf16x8 bl = *(const bf16x8*)&NMl[XIDX(nt * 16 + ml, c)];
          acc[nt] = MFMA(ah, bh, acc[nt]);
          acc[nt] = MFMA(al, bh, acc[nt]);
          acc[nt] = MFMA(ah, bl, acc[nt]);
        }
      }
      float4 bb = *(const float4*)(c1b + c0);
#pragma unroll
      for (int nt = 0; nt < 4; nt++) {
        y[nt][0] = acc[nt][0] + bb.x; y[nt][1] = acc[nt][1] + bb.y;
        y[nt][2] = acc[nt][2] + bb.z; y[nt][3] = acc[nt][3] + bb.w;
      }
    }
  }
  stats_round(0);

  // ================= econv layers (2 and 4) ===============================
  auto econv_layer = [&](const float* gam, const float* bet, const float* tw,
                         const float* tb, const float* pw, const float* pb) {
    for (int gg = 0; gg < 2; gg++) {
      int g = blk * 2 + gg;
      f32x4* y = gg ? yB : yA;
      __syncthreads();
      stage_from_regs(y, sStats, gam, bet, w, ml, kq, NMh, NMl, nullptr);
      {
        int4 v = ((const int4*)(src + (size_t)g * 1024))[t];
        int b0 = g * 64;
        U.ec.sW[t] = (unsigned)(v.x - b0) | ((unsigned)(v.y - b0) << 8) |
                     ((unsigned)(v.z - b0) << 16) | ((unsigned)(v.w - b0) << 24);
      }
      __syncthreads();
      f32x4 T[4], P[4];
#pragma unroll
      for (int nt = 0; nt < 4; nt++) {
        T[nt] = (f32x4){0.f, 0.f, 0.f, 0.f};
        P[nt] = (f32x4){0.f, 0.f, 0.f, 0.f};
      }
      const float* twr = tw + (size_t)(w * 16 + ml) * 64;
      const float* pwr = pw + (size_t)(w * 16 + ml) * 64;
#pragma unroll
      for (int kt = 0; kt < 2; kt++) {
        int c = kt * 32 + kq * 8;
        bf16x8 ath, atl, aph, apl;
        load_split8(twr + c, ath, atl);
        load_split8(pwr + c, aph, apl);
#pragma unroll
        for (int nt = 0; nt < 4; nt++) {
          bf16x8 bh = *(const bf16x8*)&NMh[XIDX(nt * 16 + ml, c)];
          bf16x8 bl = *(const bf16x8*)&NMl[XIDX(nt * 16 + ml, c)];
          T[nt] = MFMA(ath, bh, T[nt]); T[nt] = MFMA(atl, bh, T[nt]);
          T[nt] = MFMA(ath, bl, T[nt]);
          P[nt] = MFMA(aph, bh, P[nt]); P[nt] = MFMA(apl, bh, P[nt]);
          P[nt] = MFMA(aph, bl, P[nt]);
        }
      }
#pragma unroll
      for (int nt = 0; nt < 4; nt++) {
        int n = nt * 16 + ml;
        *(float4*)&U.ec.Tf[n * 68 + c0] =
            make_float4(T[nt][0], T[nt][1], T[nt][2], T[nt][3]);
      }
      float4 tbv = *(const float4*)(tb + c0);
      float4 pbv = *(const float4*)(pb + c0);
#pragma unroll
      for (int nt = 0; nt < 4; nt++) {
        int n = nt * 16 + ml;
        unsigned w0 = U.ec.sW[n * 4], w1 = U.ec.sW[n * 4 + 1],
                 w2v = U.ec.sW[n * 4 + 2], w3v = U.ec.sW[n * 4 + 3];
        float4 mn = {3.4e38f, 3.4e38f, 3.4e38f, 3.4e38f};
#pragma unroll
        for (int e = 0; e < 16; e++) {
          unsigned wd = (e < 4) ? w0 : (e < 8) ? w1 : (e < 12) ? w2v : w3v;
          int s = (wd >> ((e & 3) * 8)) & 255;
          float4 tv = *(const float4*)&U.ec.Tf[s * 68 + c0];
          mn.x = fminf(mn.x, tv.x); mn.y = fminf(mn.y, tv.y);
          mn.z = fminf(mn.z, tv.z); mn.w = fminf(mn.w, tv.w);
        }
        y[nt][0] = T[nt][0] + P[nt][0] + tbv.x + pbv.x - mn.x;
        y[nt][1] = T[nt][1] + P[nt][1] + tbv.y + pbv.y - mn.y;
        y[nt][2] = T[nt][2] + P[nt][2] + tbv.z + pbv.z - mn.z;
        y[nt][3] = T[nt][3] + P[nt][3] + tbv.w + pbv.w - mn.w;
      }
    }
  };

  // ================= cheb64 layers (3 and 5) ==============================
  auto cheb64_layer = [&](const float* gam, const float* bet, const float* W,
                          const float* bias) {
    for (int gg = 0; gg < 2; gg++) {
      int g = blk * 2 + gg;
      f32x4* y = gg ? yB : yA;
      __syncthreads();
      stage_from_regs(y, sStats, gam, bet, w, ml, kq, NMh, NMl, U.ch.C0h);
      if (w == 3) build_adj(src, g, lane, U.ch.Adj);
      __syncthreads();
      f32x4 acc[4];
#pragma unroll
      for (int nt = 0; nt < 4; nt++) acc[nt] = (f32x4){0.f, 0.f, 0.f, 0.f};
      const float* wr = W + (size_t)(w * 16 + ml) * 192;
      yacc_k64(wr, wr + 128, w, ml, kq, NMh, NMl, acc);  // W0-W2 fold @ X0
      __syncthreads();
      lap_step(U.ch.C0h, U.ch.Adj, -C1, w, ml, kq, NMh, NMl, U.ch.C1h);
      __syncthreads();
      yacc_k64(wr + 64, nullptr, w, ml, kq, NMh, NMl, acc);  // W1 @ X1
      __syncthreads();
      lap_step(U.ch.C1h, U.ch.Adj, -2.0f * C1, w, ml, kq, NMh, NMl, nullptr);
      __syncthreads();
      yacc_k64(wr + 128, nullptr, w, ml, kq, NMh, NMl, acc);  // W2 @ Z2
      float4 bb = *(const float4*)(bias + c0);
#pragma unroll
      for (int nt = 0; nt < 4; nt++) {
        y[nt][0] = acc[nt][0] + bb.x; y[nt][1] = acc[nt][1] + bb.y;
        y[nt][2] = acc[nt][2] + bb.z; y[nt][3] = acc[nt][3] + bb.w;
      }
    }
  };

  econv_layer(bn1g, bn1b, e1tw, e1tb, e1pw, e1pb);
  stats_round(1);
  cheb64_layer(bne1g, bne1b, c2w, c2b);
  stats_round(2);
  econv_layer(bn2g, bn2b, e2tw, e2tb, e2pw, e2pb);
  stats_round(3);
  cheb64_layer(bne2g, bne2b, c3w, c3b);
  stats_round(4);

  // ================= final BN+ReLU + mean pool ============================
  for (int gg = 0; gg < 2; gg++) {
    int g = blk * 2 + gg;
    f32x4* y = gg ? yB : yA;
    float sc[4], sh[4];
    bn_coeffs(sStats, bn3g, bn3b, c0, sc, sh);
    float vs[4] = {0.f, 0.f, 0.f, 0.f};
#pragma unroll
    for (int nt = 0; nt < 4; nt++)
#pragma unroll
      for (int i = 0; i < 4; i++)
        vs[i] += fmaxf(fmaf(sc[i], y[nt][i], sh[i]), 0.f);
#pragma unroll
    for (int i = 0; i < 4; i++)
#pragma unroll
      for (int off = 1; off < 16; off <<= 1) vs[i] += __shfl_xor(vs[i], off, 64);
    if (ml == 0) {
      const float r64 = 1.0f / 64.0f;
      *(float4*)(out + (size_t)g * 64 + c0) =
          make_float4(vs[0] * r64, vs[1] * r64, vs[2] * r64, vs[3] * r64);
    }
  }
}

// ---------------------------------------------------------------------------
extern "C" void kernel_launch(void* const* d_in, const int* in_sizes, int n_in,
                              void* d_out, int out_size, void* d_ws,
                              size_t ws_size, hipStream_t stream) {
  const float* feat = (const float*)d_in[0];
  const int* src = (const int*)d_in[1];
  const float* cheb1_w = (const float*)d_in[4];
  const float* cheb1_b = (const float*)d_in[5];
  const float* bn1_g = (const float*)d_in[6];
  const float* bn1_b = (const float*)d_in[7];
  const float* e1_tw = (const float*)d_in[8];
  const float* e1_tb = (const float*)d_in[9];
  const float* e1_pw = (const float*)d_in[10];
  const float* e1_pb = (const float*)d_in[11];
  const float* bne1_g = (const float*)d_in[12];
  const float* bne1_b = (const float*)d_in[13];
  const float* cheb2_w = (const float*)d_in[14];
  const float* cheb2_b = (const float*)d_in[15];
  const float* bn2_g = (const float*)d_in[16];
  const float* bn2_b = (const float*)d_in[17];
  const float* e2_tw = (const float*)d_in[18];
  const float* e2_tb = (const float*)d_in[19];
  const float* e2_pw = (const float*)d_in[20];
  const float* e2_pb = (const float*)d_in[21];
  const float* bne2_g = (const float*)d_in[22];
  const float* bne2_b = (const float*)d_in[23];
  const float* cheb3_w = (const float*)d_in[24];
  const float* cheb3_b = (const float*)d_in[25];
  const float* bn3_g = (const float*)d_in[26];
  const float* bn3_b = (const float*)d_in[27];

  float* part = (float*)d_ws;                       // 512 x 128
  float* gstats = part + 512 * 128;                 // 5 x 128
  unsigned* bar = (unsigned*)(gstats + 5 * 128);    // 10 slots x 640 B

  hipMemsetAsync(bar, 0, 8192, stream);

  k_fused<<<512, 256, 0, stream>>>(
      feat, src, cheb1_w, cheb1_b, bn1_g, bn1_b, e1_tw, e1_tb, e1_pw, e1_pb,
      bne1_g, bne1_b, cheb2_w, cheb2_b, bn2_g, bn2_b, e2_tw, e2_tb, e2_pw,
      e2_pb, bne2_g, bne2_b, cheb3_w, cheb3_b, bn3_g, bn3_b, (float*)d_out,
      part, gstats, bar);
}

// Round 6
// 295.570 us; speedup vs baseline: 1.6087x; 1.0319x over previous
//
#include <hip/hip_runtime.h>

#define EPSF 1e-5f
#define C1 0.0625f

typedef short bf16x8 __attribute__((ext_vector_type(8)));
typedef short s16x4 __attribute__((ext_vector_type(4)));
typedef float f32x4 __attribute__((ext_vector_type(4)));
typedef unsigned short u16;

#define MFMA(a, b, c) __builtin_amdgcn_mfma_f32_16x16x32_bf16(a, b, c, 0, 0, 0)

// coherent (cross-XCD) scalar access helpers — lower to global_* with sc1.
__device__ __forceinline__ void cstore(float* p, float v) {
  __hip_atomic_store(p, v, __ATOMIC_RELAXED, __HIP_MEMORY_SCOPE_AGENT);
}
__device__ __forceinline__ float cload(const float* p) {
  return __hip_atomic_load(p, __ATOMIC_RELAXED, __HIP_MEMORY_SCOPE_AGENT);
}

__device__ __forceinline__ u16 f2bf(float x) {
  union { float f; unsigned u; } v; v.f = x;
  unsigned r = v.u + 0x7fffu + ((v.u >> 16) & 1u);
  return (u16)(r >> 16);
}
__device__ __forceinline__ float bf2f(u16 h) {
  union { float f; unsigned u; } v; v.u = ((unsigned)h) << 16; return v.f;
}
__device__ __forceinline__ void split2(float x, u16& h, u16& l) {
  h = f2bf(x); l = f2bf(x - bf2f(h));
}
// swizzled index into a 64x64 u16 LDS tile: 16B granules XOR'd by row&7
__device__ __forceinline__ int XIDX(int r, int c) {
  return r * 64 + ((((c >> 3) ^ (r & 7)) << 3) | (c & 7));
}

// LDS overlay: cheb layers need C0h/C1h/Adj; econv needs Tf + sW.
struct ChebSh { u16 C0h[4096]; u16 C1h[4096]; u16 Adj[4096]; };
struct EcSh { float Tf[64 * 68]; unsigned sW[256]; };
union USh { ChebSh ch; EcSh ec; };

// ---------------------------------------------------------------------------
// global barrier: monotonic counters, fresh slot per use (zeroed by memset).
// ---------------------------------------------------------------------------
__device__ __forceinline__ void gbarrier(unsigned* bar, int slot, int blk) {
  __syncthreads();
  if (threadIdx.x == 0) {
    __builtin_amdgcn_s_waitcnt(0);
    unsigned* base = bar + slot * 160;
    unsigned old = atomicAdd(base + (blk & 7) * 16, 1u);
    if (old == 63u) atomicAdd(base + 128, 1u);
    while (__hip_atomic_load(base + 128, __ATOMIC_RELAXED,
                             __HIP_MEMORY_SCOPE_AGENT) < 8u)
      __builtin_amdgcn_s_sleep(4);
  }
  __syncthreads();
}

// Build local adjacency multiplicity matrix (bf16 exact ints <=16), wave 3.
__device__ __forceinline__ void build_adj(const int* __restrict__ src, int g,
                                          int r, u16* Adj) {
  bf16x8 z = {0, 0, 0, 0, 0, 0, 0, 0};
#pragma unroll
  for (int q = 0; q < 8; q++) *(bf16x8*)&Adj[r * 64 + q * 8] = z;
  const int4* s4 = (const int4*)(src + (size_t)g * 1024 + (size_t)r * 16);
  int4 a0 = s4[0], a1 = s4[1], a2 = s4[2], a3 = s4[3];
  int b0 = g * 64;
  int ss[16] = {a0.x - b0, a0.y - b0, a0.z - b0, a0.w - b0,
                a1.x - b0, a1.y - b0, a1.z - b0, a1.w - b0,
                a2.x - b0, a2.y - b0, a2.z - b0, a2.w - b0,
                a3.x - b0, a3.y - b0, a3.z - b0, a3.w - b0};
#pragma unroll
  for (int e = 0; e < 16; e++) {
    int idx = XIDX(r, ss[e]);
    Adj[idx] = f2bf(bf2f(Adj[idx]) + 1.0f);
  }
}

// load 8 fp32 weights, split to bf16 hi/lo frags
__device__ __forceinline__ void load_split8(const float* p, bf16x8& h, bf16x8& l) {
  float4 v0 = *(const float4*)p;
  float4 v1 = *(const float4*)(p + 4);
  float vv[8] = {v0.x, v0.y, v0.z, v0.w, v1.x, v1.y, v1.z, v1.w};
#pragma unroll
  for (int j = 0; j < 8; j++) {
    u16 hh, ll; split2(vv[j], hh, ll);
    h[j] = (short)hh; l[j] = (short)ll;
  }
}
__device__ __forceinline__ void load_split8_sub(const float* p, const float* q,
                                                bf16x8& h, bf16x8& l) {
  float4 v0 = *(const float4*)p;
  float4 v1 = *(const float4*)(p + 4);
  float4 u0 = *(const float4*)q;
  float4 u1 = *(const float4*)(q + 4);
  float vv[8] = {v0.x - u0.x, v0.y - u0.y, v0.z - u0.z, v0.w - u0.w,
                 v1.x - u1.x, v1.y - u1.y, v1.z - u1.z, v1.w - u1.w};
#pragma unroll
  for (int j = 0; j < 8; j++) {
    u16 hh, ll; split2(vv[j], hh, ll);
    h[j] = (short)hh; l[j] = (short)ll;
  }
}

__device__ __forceinline__ void bn_coeffs(const float* sStats, const float* gam,
                                          const float* bet, int c0, float* sc,
                                          float* sh) {
  const float inv = 1.0f / 65536.0f;
#pragma unroll
  for (int i = 0; i < 4; i++) {
    float m1 = sStats[c0 + i] * inv;
    float var = fmaf(sStats[64 + c0 + i], inv, -m1 * m1);
    float s = gam[c0 + i] * rsqrtf(var + EPSF);
    sc[i] = s;
    sh[i] = fmaf(-m1, s, bet[c0 + i]);
  }
}

// BN+ReLU register-held pre-BN y, stage into NM (hi/lo) + optional CM(hi).
__device__ __forceinline__ void stage_from_regs(const f32x4 (&y)[4],
                                                const float* sStats,
                                                const float* gam,
                                                const float* bet, int w, int ml,
                                                int kq, u16* NMh, u16* NMl,
                                                u16* CMh) {
  int c0 = w * 16 + kq * 4;
  float sc[4], sh[4];
  bn_coeffs(sStats, gam, bet, c0, sc, sh);
#pragma unroll
  for (int nt = 0; nt < 4; nt++) {
    int n = nt * 16 + ml;
    u16 hh[4], ll[4];
#pragma unroll
    for (int i = 0; i < 4; i++) {
      float h = fmaxf(fmaf(sc[i], y[nt][i], sh[i]), 0.f);
      split2(h, hh[i], ll[i]);
    }
    s16x4 vh, vl;
#pragma unroll
    for (int i = 0; i < 4; i++) { vh[i] = (short)hh[i]; vl[i] = (short)ll[i]; }
    *(s16x4*)&NMh[XIDX(n, c0)] = vh;
    *(s16x4*)&NMl[XIDX(n, c0)] = vl;
    if (CMh) {
#pragma unroll
      for (int i = 0; i < 4; i++) CMh[XIDX(c0 + i, n)] = (u16)hh[i];
    }
  }
}

// X_next = scale * Adj * X (X read ch-major hi-only); out -> NM (hi/lo) + opt CM
__device__ __forceinline__ void lap_step(const u16* Bh, const u16* Adj,
                                         float scale, int w, int ml, int kq,
                                         u16* NMh, u16* NMl, u16* oCh) {
  f32x4 l[4];
#pragma unroll
  for (int nt = 0; nt < 4; nt++) l[nt] = (f32x4){0.f, 0.f, 0.f, 0.f};
#pragma unroll
  for (int kt = 0; kt < 2; kt++) {
    int kk = kt * 32 + kq * 8;
    bf16x8 aa = *(const bf16x8*)&Adj[XIDX(w * 16 + ml, kk)];
#pragma unroll
    for (int nt = 0; nt < 4; nt++) {
      bf16x8 bh = *(const bf16x8*)&Bh[XIDX(nt * 16 + ml, kk)];
      l[nt] = MFMA(aa, bh, l[nt]);
    }
  }
  int r0 = w * 16 + kq * 4;
#pragma unroll
  for (int nt = 0; nt < 4; nt++) {
    int c = nt * 16 + ml;
    u16 hh[4], ll[4];
#pragma unroll
    for (int i = 0; i < 4; i++) {
      split2(l[nt][i] * scale, hh[i], ll[i]);
      NMh[XIDX(r0 + i, c)] = hh[i];
      NMl[XIDX(r0 + i, c)] = ll[i];
    }
    if (oCh) {
      s16x4 vh;
#pragma unroll
      for (int i = 0; i < 4; i++) vh[i] = (short)hh[i];
      *(s16x4*)&oCh[XIDX(c, r0)] = vh;
    }
  }
}

// acc += W[:, k0..k0+63] (fp32, split in-reg; optional fold subtrahend) @ X
__device__ __forceinline__ void yacc_k64(const float* wrow, const float* wfold,
                                         int w, int ml, int kq, const u16* NMh,
                                         const u16* NMl, f32x4 (&acc)[4]) {
#pragma unroll
  for (int kt = 0; kt < 2; kt++) {
    int c = kt * 32 + kq * 8;
    bf16x8 ah, al;
    if (wfold) load_split8_sub(wrow + c, wfold + c, ah, al);
    else load_split8(wrow + c, ah, al);
#pragma unroll
    for (int nt = 0; nt < 4; nt++) {
      bf16x8 bh = *(const bf16x8*)&NMh[XIDX(nt * 16 + ml, c)];
      bf16x8 bl = *(const bf16x8*)&NMl[XIDX(nt * 16 + ml, c)];
      acc[nt] = MFMA(ah, bh, acc[nt]);
      acc[nt] = MFMA(al, bh, acc[nt]);
      acc[nt] = MFMA(ah, bl, acc[nt]);
    }
  }
}

// ---------------------------------------------------------------------------
__global__ __launch_bounds__(256, 3) void k_fused(
    const float* __restrict__ feat, const int* __restrict__ src,
    const float* __restrict__ c1w, const float* __restrict__ c1b,
    const float* __restrict__ bn1g, const float* __restrict__ bn1b,
    const float* __restrict__ e1tw, const float* __restrict__ e1tb,
    const float* __restrict__ e1pw, const float* __restrict__ e1pb,
    const float* __restrict__ bne1g, const float* __restrict__ bne1b,
    const float* __restrict__ c2w, const float* __restrict__ c2b,
    const float* __restrict__ bn2g, const float* __restrict__ bn2b,
    const float* __restrict__ e2tw, const float* __restrict__ e2tb,
    const float* __restrict__ e2pw, const float* __restrict__ e2pb,
    const float* __restrict__ bne2g, const float* __restrict__ bne2b,
    const float* __restrict__ c3w, const float* __restrict__ c3b,
    const float* __restrict__ bn3g, const float* __restrict__ bn3b,
    float* __restrict__ out, float* __restrict__ part,
    float* __restrict__ gstats, unsigned* __restrict__ bar) {
  __shared__ __align__(16) u16 NMh[4096];
  __shared__ __align__(16) u16 NMl[4096];
  __shared__ __align__(16) USh U;
  __shared__ float sStats[128];
  __shared__ float sRed[256];

  const int t = threadIdx.x, blk = blockIdx.x;
  const int lane = t & 63;
  const int w = __builtin_amdgcn_readfirstlane(t >> 6);
  const int ml = lane & 15, kq = lane >> 4;
  const int c0 = w * 16 + kq * 4;
  float* prow = part + (size_t)blk * 128;

  // activations for the block's two graphs — ALWAYS referenced by name
  // (no runtime-selected pointer!) so they stay in VGPRs.
  f32x4 yA[4], yB[4];

  // ---- per-layer stats round: partials -> barrier -> reduce -> barrier ----
  auto stats_round = [&](int L) {
    float s1[4] = {0.f, 0.f, 0.f, 0.f}, s2[4] = {0.f, 0.f, 0.f, 0.f};
#pragma unroll
    for (int nt = 0; nt < 4; nt++) {
#pragma unroll
      for (int i = 0; i < 4; i++) {
        float a = yA[nt][i], b = yB[nt][i];
        s1[i] += a + b;
        s2[i] += a * a + b * b;
      }
    }
#pragma unroll
    for (int i = 0; i < 4; i++) {
#pragma unroll
      for (int off = 1; off < 16; off <<= 1) {
        s1[i] += __shfl_xor(s1[i], off, 64);
        s2[i] += __shfl_xor(s2[i], off, 64);
      }
    }
    if (ml == 0) {
#pragma unroll
      for (int i = 0; i < 4; i++) {
        cstore(prow + c0 + i, s1[i]);
        cstore(prow + 64 + c0 + i, s2[i]);
      }
    }
    gbarrier(bar, L * 2, blk);
    if (blk < 8) {
      int cc = t & 15, rg = t >> 4;
      const float* pp = part + (size_t)(rg * 32) * 128 + blk * 16 + cc;
      float a = 0.f;
#pragma unroll 8
      for (int r = 0; r < 32; r++) a += cload(pp + (size_t)r * 128);
      sRed[t] = a;
      __syncthreads();
      if (t < 16) {
        float s = 0.f;
#pragma unroll
        for (int k = 0; k < 16; k++) s += sRed[k * 16 + t];
        cstore(gstats + L * 128 + blk * 16 + t, s);
      }
    }
    gbarrier(bar, L * 2 + 1, blk);
    if (t < 128) sStats[t] = cload(gstats + L * 128 + t);
    __syncthreads();
  };

  // ================= Layer 1: cheb1 (FIN=16, K padded to 64) ==============
  auto cheb1_graph = [&](int g, f32x4 (&y)[4]) {
    __syncthreads();
    {  // stage X0 = feat (node t>>2, ch (t&3)*4..+3); CM hi into U.ch.C0h
      int n = t >> 2, cc0 = (t & 3) * 4;
      float4 v = *(const float4*)(feat + (size_t)(g * 64 + n) * 16 + cc0);
      u16 hh[4], ll[4];
      split2(v.x, hh[0], ll[0]); split2(v.y, hh[1], ll[1]);
      split2(v.z, hh[2], ll[2]); split2(v.w, hh[3], ll[3]);
      s16x4 vh, vl;
#pragma unroll
      for (int i = 0; i < 4; i++) { vh[i] = (short)hh[i]; vl[i] = (short)ll[i]; }
      *(s16x4*)&NMh[XIDX(n, cc0)] = vh;
      *(s16x4*)&NMl[XIDX(n, cc0)] = vl;
#pragma unroll
      for (int i = 0; i < 4; i++) U.ch.C0h[XIDX(cc0 + i, n)] = (u16)hh[i];
    }
    if (w == 0) {
      bf16x8 z = {0, 0, 0, 0, 0, 0, 0, 0};
      *(bf16x8*)&NMh[XIDX(lane, 48)] = z;
      *(bf16x8*)&NMh[XIDX(lane, 56)] = z;
    } else if (w == 1) {
      bf16x8 z = {0, 0, 0, 0, 0, 0, 0, 0};
      *(bf16x8*)&NMl[XIDX(lane, 48)] = z;
      *(bf16x8*)&NMl[XIDX(lane, 56)] = z;
    } else if (w == 3) {
      build_adj(src, g, lane, U.ch.Adj);
    }
    __syncthreads();
    {  // lap1: X1 (chs 0..15) -> NM cols 16..31 (hi/lo) + CM rows 16..31 (hi)
      f32x4 l = {0.f, 0.f, 0.f, 0.f};
#pragma unroll
      for (int kt = 0; kt < 2; kt++) {
        int kk = kt * 32 + kq * 8;
        bf16x8 aa = *(const bf16x8*)&U.ch.Adj[XIDX(w * 16 + ml, kk)];
        bf16x8 bh = *(const bf16x8*)&U.ch.C0h[XIDX(ml, kk)];
        l = MFMA(aa, bh, l);
      }
      int r0 = w * 16 + kq * 4;
      u16 hh[4], ll[4];
#pragma unroll
      for (int i = 0; i < 4; i++) {
        split2(l[i] * (-C1), hh[i], ll[i]);
        NMh[XIDX(r0 + i, 16 + ml)] = hh[i];
        NMl[XIDX(r0 + i, 16 + ml)] = ll[i];
      }
      s16x4 vh;
#pragma unroll
      for (int i = 0; i < 4; i++) vh[i] = (short)hh[i];
      *(s16x4*)&U.ch.C0h[XIDX(16 + ml, r0)] = vh;
    }
    __syncthreads();
    {  // lap2: Z2 = -2C1*Adj*X1 -> NM cols 32..47
      f32x4 l = {0.f, 0.f, 0.f, 0.f};
#pragma unroll
      for (int kt = 0; kt < 2; kt++) {
        int kk = kt * 32 + kq * 8;
        bf16x8 aa = *(const bf16x8*)&U.ch.Adj[XIDX(w * 16 + ml, kk)];
        bf16x8 bh = *(const bf16x8*)&U.ch.C0h[XIDX(16 + ml, kk)];
        l = MFMA(aa, bh, l);
      }
      int r0 = w * 16 + kq * 4;
#pragma unroll
      for (int i = 0; i < 4; i++) {
        u16 hh, ll;
        split2(l[i] * (-2.0f * C1), hh, ll);
        NMh[XIDX(r0 + i, 32 + ml)] = hh;
        NMl[XIDX(r0 + i, 32 + ml)] = ll;
      }
    }
    __syncthreads();
    {  // Y = Xcat @ Wfold^T (K=64, fp32 W with in-reg fold/split)
      f32x4 acc[4];
#pragma unroll
      for (int nt = 0; nt < 4; nt++) acc[nt] = (f32x4){0.f, 0.f, 0.f, 0.f};
      const float* wr = c1w + (size_t)(w * 16 + ml) * 48;
#pragma unroll
      for (int kt = 0; kt < 2; kt++) {
        int c = kt * 32 + kq * 8;
        float vv[8];
        if (c < 16) {
          float4 a0 = *(const float4*)(wr + c), a1 = *(const float4*)(wr + c + 4);
          float4 b0 = *(const float4*)(wr + 32 + c),
                 b1 = *(const float4*)(wr + 32 + c + 4);
          vv[0] = a0.x - b0.x; vv[1] = a0.y - b0.y; vv[2] = a0.z - b0.z;
          vv[3] = a0.w - b0.w; vv[4] = a1.x - b1.x; vv[5] = a1.y - b1.y;
          vv[6] = a1.z - b1.z; vv[7] = a1.w - b1.w;
        } else if (c < 48) {
          float4 a0 = *(const float4*)(wr + c), a1 = *(const float4*)(wr + c + 4);
          vv[0] = a0.x; vv[1] = a0.y; vv[2] = a0.z; vv[3] = a0.w;
          vv[4] = a1.x; vv[5] = a1.y; vv[6] = a1.z; vv[7] = a1.w;
        } else {
#pragma unroll
          for (int j = 0; j < 8; j++) vv[j] = 0.f;
        }
        bf16x8 ah, al;
#pragma unroll
        for (int j = 0; j < 8; j++) {
          u16 hh, ll; split2(vv[j], hh, ll);
          ah[j] = (short)hh; al[j] = (short)ll;
        }
#pragma unroll
        for (int nt = 0; nt < 4; nt++) {
          bf16x8 bh = *(const bf16x8*)&NMh[XIDX(nt * 16 + ml, c)];
          bf16x8 bl = *(const bf16x8*)&NMl[XIDX(nt * 16 + ml, c)];
          acc[nt] = MFMA(ah, bh, acc[nt]);
          acc[nt] = MFMA(al, bh, acc[nt]);
          acc[nt] = MFMA(ah, bl, acc[nt]);
        }
      }
      float4 bb = *(const float4*)(c1b + c0);
#pragma unroll
      for (int nt = 0; nt < 4; nt++) {
        y[nt][0] = acc[nt][0] + bb.x; y[nt][1] = acc[nt][1] + bb.y;
        y[nt][2] = acc[nt][2] + bb.z; y[nt][3] = acc[nt][3] + bb.w;
      }
    }
  };
  cheb1_graph(blk * 2, yA);
  cheb1_graph(blk * 2 + 1, yB);
  stats_round(0);

  // ================= econv layers (2 and 4) ===============================
  auto econv_graph = [&](const float* gam, const float* bet, const float* tw,
                         const float* tb, const float* pw, const float* pb,
                         int g, f32x4 (&y)[4]) {
    __syncthreads();
    stage_from_regs(y, sStats, gam, bet, w, ml, kq, NMh, NMl, nullptr);
    {
      int4 v = ((const int4*)(src + (size_t)g * 1024))[t];
      int b0 = g * 64;
      U.ec.sW[t] = (unsigned)(v.x - b0) | ((unsigned)(v.y - b0) << 8) |
                   ((unsigned)(v.z - b0) << 16) | ((unsigned)(v.w - b0) << 24);
    }
    __syncthreads();
    f32x4 T[4], P[4];
#pragma unroll
    for (int nt = 0; nt < 4; nt++) {
      T[nt] = (f32x4){0.f, 0.f, 0.f, 0.f};
      P[nt] = (f32x4){0.f, 0.f, 0.f, 0.f};
    }
    const float* twr = tw + (size_t)(w * 16 + ml) * 64;
    const float* pwr = pw + (size_t)(w * 16 + ml) * 64;
#pragma unroll
    for (int kt = 0; kt < 2; kt++) {
      int c = kt * 32 + kq * 8;
      bf16x8 ath, atl, aph, apl;
      load_split8(twr + c, ath, atl);
      load_split8(pwr + c, aph, apl);
#pragma unroll
      for (int nt = 0; nt < 4; nt++) {
        bf16x8 bh = *(const bf16x8*)&NMh[XIDX(nt * 16 + ml, c)];
        bf16x8 bl = *(const bf16x8*)&NMl[XIDX(nt * 16 + ml, c)];
        T[nt] = MFMA(ath, bh, T[nt]); T[nt] = MFMA(atl, bh, T[nt]);
        T[nt] = MFMA(ath, bl, T[nt]);
        P[nt] = MFMA(aph, bh, P[nt]); P[nt] = MFMA(apl, bh, P[nt]);
        P[nt] = MFMA(aph, bl, P[nt]);
      }
    }
#pragma unroll
    for (int nt = 0; nt < 4; nt++) {
      int n = nt * 16 + ml;
      *(float4*)&U.ec.Tf[n * 68 + c0] =
          make_float4(T[nt][0], T[nt][1], T[nt][2], T[nt][3]);
    }
    float4 tbv = *(const float4*)(tb + c0);
    float4 pbv = *(const float4*)(pb + c0);
#pragma unroll
    for (int nt = 0; nt < 4; nt++) {
      int n = nt * 16 + ml;
      unsigned w0 = U.ec.sW[n * 4], w1 = U.ec.sW[n * 4 + 1],
               w2v = U.ec.sW[n * 4 + 2], w3v = U.ec.sW[n * 4 + 3];
      float4 mn = {3.4e38f, 3.4e38f, 3.4e38f, 3.4e38f};
#pragma unroll
      for (int e = 0; e < 16; e++) {
        unsigned wd = (e < 4) ? w0 : (e < 8) ? w1 : (e < 12) ? w2v : w3v;
        int s = (wd >> ((e & 3) * 8)) & 255;
        float4 tv = *(const float4*)&U.ec.Tf[s * 68 + c0];
        mn.x = fminf(mn.x, tv.x); mn.y = fminf(mn.y, tv.y);
        mn.z = fminf(mn.z, tv.z); mn.w = fminf(mn.w, tv.w);
      }
      y[nt][0] = T[nt][0] + P[nt][0] + tbv.x + pbv.x - mn.x;
      y[nt][1] = T[nt][1] + P[nt][1] + tbv.y + pbv.y - mn.y;
      y[nt][2] = T[nt][2] + P[nt][2] + tbv.z + pbv.z - mn.z;
      y[nt][3] = T[nt][3] + P[nt][3] + tbv.w + pbv.w - mn.w;
    }
  };

  // ================= cheb64 layers (3 and 5) ==============================
  auto cheb64_graph = [&](const float* gam, const float* bet, const float* W,
                          const float* bias, int g, f32x4 (&y)[4]) {
    __syncthreads();
    stage_from_regs(y, sStats, gam, bet, w, ml, kq, NMh, NMl, U.ch.C0h);
    if (w == 3) build_adj(src, g, lane, U.ch.Adj);
    __syncthreads();
    f32x4 acc[4];
#pragma unroll
    for (int nt = 0; nt < 4; nt++) acc[nt] = (f32x4){0.f, 0.f, 0.f, 0.f};
    const float* wr = W + (size_t)(w * 16 + ml) * 192;
    yacc_k64(wr, wr + 128, w, ml, kq, NMh, NMl, acc);  // W0-W2 fold @ X0
    __syncthreads();
    lap_step(U.ch.C0h, U.ch.Adj, -C1, w, ml, kq, NMh, NMl, U.ch.C1h);
    __syncthreads();
    yacc_k64(wr + 64, nullptr, w, ml, kq, NMh, NMl, acc);  // W1 @ X1
    __syncthreads();
    lap_step(U.ch.C1h, U.ch.Adj, -2.0f * C1, w, ml, kq, NMh, NMl, nullptr);
    __syncthreads();
    yacc_k64(wr + 128, nullptr, w, ml, kq, NMh, NMl, acc);  // W2 @ Z2
    float4 bb = *(const float4*)(bias + c0);
#pragma unroll
    for (int nt = 0; nt < 4; nt++) {
      y[nt][0] = acc[nt][0] + bb.x; y[nt][1] = acc[nt][1] + bb.y;
      y[nt][2] = acc[nt][2] + bb.z; y[nt][3] = acc[nt][3] + bb.w;
    }
  };

  econv_graph(bn1g, bn1b, e1tw, e1tb, e1pw, e1pb, blk * 2, yA);
  econv_graph(bn1g, bn1b, e1tw, e1tb, e1pw, e1pb, blk * 2 + 1, yB);
  stats_round(1);
  cheb64_graph(bne1g, bne1b, c2w, c2b, blk * 2, yA);
  cheb64_graph(bne1g, bne1b, c2w, c2b, blk * 2 + 1, yB);
  stats_round(2);
  econv_graph(bn2g, bn2b, e2tw, e2tb, e2pw, e2pb, blk * 2, yA);
  econv_graph(bn2g, bn2b, e2tw, e2tb, e2pw, e2pb, blk * 2 + 1, yB);
  stats_round(3);
  cheb64_graph(bne2g, bne2b, c3w, c3b, blk * 2, yA);
  cheb64_graph(bne2g, bne2b, c3w, c3b, blk * 2 + 1, yB);
  stats_round(4);

  // ================= final BN+ReLU + mean pool ============================
  auto pool_graph = [&](int g, const f32x4 (&y)[4]) {
    float sc[4], sh[4];
    bn_coeffs(sStats, bn3g, bn3b, c0, sc, sh);
    float vs[4] = {0.f, 0.f, 0.f, 0.f};
#pragma unroll
    for (int nt = 0; nt < 4; nt++)
#pragma unroll
      for (int i = 0; i < 4; i++)
        vs[i] += fmaxf(fmaf(sc[i], y[nt][i], sh[i]), 0.f);
#pragma unroll
    for (int i = 0; i < 4; i++)
#pragma unroll
      for (int off = 1; off < 16; off <<= 1) vs[i] += __shfl_xor(vs[i], off, 64);
    if (ml == 0) {
      const float r64 = 1.0f / 64.0f;
      *(float4*)(out + (size_t)g * 64 + c0) =
          make_float4(vs[0] * r64, vs[1] * r64, vs[2] * r64, vs[3] * r64);
    }
  };
  pool_graph(blk * 2, yA);
  pool_graph(blk * 2 + 1, yB);
}

// ---------------------------------------------------------------------------
extern "C" void kernel_launch(void* const* d_in, const int* in_sizes, int n_in,
                              void* d_out, int out_size, void* d_ws,
                              size_t ws_size, hipStream_t stream) {
  const float* feat = (const float*)d_in[0];
  const int* src = (const int*)d_in[1];
  const float* cheb1_w = (const float*)d_in[4];
  const float* cheb1_b = (const float*)d_in[5];
  const float* bn1_g = (const float*)d_in[6];
  const float* bn1_b = (const float*)d_in[7];
  const float* e1_tw = (const float*)d_in[8];
  const float* e1_tb = (const float*)d_in[9];
  const float* e1_pw = (const float*)d_in[10];
  const float* e1_pb = (const float*)d_in[11];
  const float* bne1_g = (const float*)d_in[12];
  const float* bne1_b = (const float*)d_in[13];
  const float* cheb2_w = (const float*)d_in[14];
  const float* cheb2_b = (const float*)d_in[15];
  const float* bn2_g = (const float*)d_in[16];
  const float* bn2_b = (const float*)d_in[17];
  const float* e2_tw = (const float*)d_in[18];
  const float* e2_tb = (const float*)d_in[19];
  const float* e2_pw = (const float*)d_in[20];
  const float* e2_pb = (const float*)d_in[21];
  const float* bne2_g = (const float*)d_in[22];
  const float* bne2_b = (const float*)d_in[23];
  const float* cheb3_w = (const float*)d_in[24];
  const float* cheb3_b = (const float*)d_in[25];
  const float* bn3_g = (const float*)d_in[26];
  const float* bn3_b = (const float*)d_in[27];

  float* part = (float*)d_ws;                       // 512 x 128
  float* gstats = part + 512 * 128;                 // 5 x 128
  unsigned* bar = (unsigned*)(gstats + 5 * 128);    // 10 slots x 640 B

  hipMemsetAsync(bar, 0, 8192, stream);

  k_fused<<<512, 256, 0, stream>>>(
      feat, src, cheb1_w, cheb1_b, bn1_g, bn1_b, e1_tw, e1_tb, e1_pw, e1_pb,
      bne1_g, bne1_b, cheb2_w, cheb2_b, bn2_g, bn2_b, e2_tw, e2_tb, e2_pw,
      e2_pb, bne2_g, bne2_b, cheb3_w, cheb3_b, bn3_g, bn3_b, (float*)d_out,
      part, gstats, bar);
}

// Round 7
// 241.389 us; speedup vs baseline: 1.9698x; 1.2245x over previous
//
#include <hip/hip_runtime.h>

#define EPSF 1e-5f
#define C1 0.0625f

typedef short bf16x8 __attribute__((ext_vector_type(8)));
typedef short s16x4 __attribute__((ext_vector_type(4)));
typedef float f32x4 __attribute__((ext_vector_type(4)));
typedef unsigned short u16;

#define MFMA(a, b, c) __builtin_amdgcn_mfma_f32_16x16x32_bf16(a, b, c, 0, 0, 0)

// coherent (cross-XCD) scalar access helpers — lower to global_* with sc1.
__device__ __forceinline__ void cstore(float* p, float v) {
  __hip_atomic_store(p, v, __ATOMIC_RELAXED, __HIP_MEMORY_SCOPE_AGENT);
}
__device__ __forceinline__ float cload(const float* p) {
  return __hip_atomic_load(p, __ATOMIC_RELAXED, __HIP_MEMORY_SCOPE_AGENT);
}

__device__ __forceinline__ u16 f2bf(float x) {
  union { float f; unsigned u; } v; v.f = x;
  unsigned r = v.u + 0x7fffu + ((v.u >> 16) & 1u);
  return (u16)(r >> 16);
}
__device__ __forceinline__ float bf2f(u16 h) {
  union { float f; unsigned u; } v; v.u = ((unsigned)h) << 16; return v.f;
}
__device__ __forceinline__ void split2(float x, u16& h, u16& l) {
  h = f2bf(x); l = f2bf(x - bf2f(h));
}
// swizzled index into a 64x64 u16 LDS tile: 16B granules XOR'd by row&7
__device__ __forceinline__ int XIDX(int r, int c) {
  return r * 64 + ((((c >> 3) ^ (r & 7)) << 3) | (c & 7));
}

// LDS overlay: cheb layers need C0h/C1h/Adj; econv needs Tf + sW.
struct ChebSh { u16 C0h[4096]; u16 C1h[4096]; u16 Adj[4096]; };
struct EcSh { float Tf[64 * 68]; unsigned sW[256]; };
union USh { ChebSh ch; EcSh ec; };

// ---------------------------------------------------------------------------
__device__ __forceinline__ void gbarrier(unsigned* bar, int slot, int blk) {
  __syncthreads();
  if (threadIdx.x == 0) {
    __builtin_amdgcn_s_waitcnt(0);
    unsigned* base = bar + slot * 160;
    unsigned old = atomicAdd(base + (blk & 7) * 16, 1u);
    if (old == 63u) atomicAdd(base + 128, 1u);
    while (__hip_atomic_load(base + 128, __ATOMIC_RELAXED,
                             __HIP_MEMORY_SCOPE_AGENT) < 8u)
      __builtin_amdgcn_s_sleep(4);
  }
  __syncthreads();
}

// Build local adjacency multiplicity matrix (bf16 exact ints <=16), wave 3.
__device__ __forceinline__ void build_adj(const int* __restrict__ src, int g,
                                          int r, u16* Adj) {
  bf16x8 z = {0, 0, 0, 0, 0, 0, 0, 0};
#pragma unroll
  for (int q = 0; q < 8; q++) *(bf16x8*)&Adj[r * 64 + q * 8] = z;
  const int4* s4 = (const int4*)(src + (size_t)g * 1024 + (size_t)r * 16);
  int4 a0 = s4[0], a1 = s4[1], a2 = s4[2], a3 = s4[3];
  int b0 = g * 64;
  int ss[16] = {a0.x - b0, a0.y - b0, a0.z - b0, a0.w - b0,
                a1.x - b0, a1.y - b0, a1.z - b0, a1.w - b0,
                a2.x - b0, a2.y - b0, a2.z - b0, a2.w - b0,
                a3.x - b0, a3.y - b0, a3.z - b0, a3.w - b0};
#pragma unroll
  for (int e = 0; e < 16; e++) {
    int idx = XIDX(r, ss[e]);
    Adj[idx] = f2bf(bf2f(Adj[idx]) + 1.0f);
  }
}

// load 8 fp32 weights, split to bf16 hi/lo frags
__device__ __forceinline__ void load_split8(const float* p, bf16x8& h, bf16x8& l) {
  float4 v0 = *(const float4*)p;
  float4 v1 = *(const float4*)(p + 4);
  float vv[8] = {v0.x, v0.y, v0.z, v0.w, v1.x, v1.y, v1.z, v1.w};
#pragma unroll
  for (int j = 0; j < 8; j++) {
    u16 hh, ll; split2(vv[j], hh, ll);
    h[j] = (short)hh; l[j] = (short)ll;
  }
}
__device__ __forceinline__ void load_split8_sub(const float* p, const float* q,
                                                bf16x8& h, bf16x8& l) {
  float4 v0 = *(const float4*)p;
  float4 v1 = *(const float4*)(p + 4);
  float4 u0 = *(const float4*)q;
  float4 u1 = *(const float4*)(q + 4);
  float vv[8] = {v0.x - u0.x, v0.y - u0.y, v0.z - u0.z, v0.w - u0.w,
                 v1.x - u1.x, v1.y - u1.y, v1.z - u1.z, v1.w - u1.w};
#pragma unroll
  for (int j = 0; j < 8; j++) {
    u16 hh, ll; split2(vv[j], hh, ll);
    h[j] = (short)hh; l[j] = (short)ll;
  }
}

__device__ __forceinline__ void bn_coeffs(const float* sStats, const float* gam,
                                          const float* bet, int c0, float* sc,
                                          float* sh) {
  const float inv = 1.0f / 65536.0f;
#pragma unroll
  for (int i = 0; i < 4; i++) {
    float m1 = sStats[c0 + i] * inv;
    float var = fmaf(sStats[64 + c0 + i], inv, -m1 * m1);
    float s = gam[c0 + i] * rsqrtf(var + EPSF);
    sc[i] = s;
    sh[i] = fmaf(-m1, s, bet[c0 + i]);
  }
}

// BN+ReLU register-held pre-BN y, stage into NM (hi/lo) + optional CM(hi).
__device__ __forceinline__ void stage_from_regs(const f32x4 (&y)[4],
                                                const float* sStats,
                                                const float* gam,
                                                const float* bet, int w, int ml,
                                                int kq, u16* NMh, u16* NMl,
                                                u16* CMh) {
  int c0 = w * 16 + kq * 4;
  float sc[4], sh[4];
  bn_coeffs(sStats, gam, bet, c0, sc, sh);
#pragma unroll
  for (int nt = 0; nt < 4; nt++) {
    int n = nt * 16 + ml;
    u16 hh[4], ll[4];
#pragma unroll
    for (int i = 0; i < 4; i++) {
      float h = fmaxf(fmaf(sc[i], y[nt][i], sh[i]), 0.f);
      split2(h, hh[i], ll[i]);
    }
    s16x4 vh, vl;
#pragma unroll
    for (int i = 0; i < 4; i++) { vh[i] = (short)hh[i]; vl[i] = (short)ll[i]; }
    *(s16x4*)&NMh[XIDX(n, c0)] = vh;
    *(s16x4*)&NMl[XIDX(n, c0)] = vl;
    if (CMh) {
#pragma unroll
      for (int i = 0; i < 4; i++) CMh[XIDX(c0 + i, n)] = (u16)hh[i];
    }
  }
}

// X_next = scale * Adj * X (X read ch-major hi-only); out -> NM (hi/lo) + opt CM
__device__ __forceinline__ void lap_step(const u16* Bh, const u16* Adj,
                                         float scale, int w, int ml, int kq,
                                         u16* NMh, u16* NMl, u16* oCh) {
  f32x4 l[4];
#pragma unroll
  for (int nt = 0; nt < 4; nt++) l[nt] = (f32x4){0.f, 0.f, 0.f, 0.f};
#pragma unroll
  for (int kt = 0; kt < 2; kt++) {
    int kk = kt * 32 + kq * 8;
    bf16x8 aa = *(const bf16x8*)&Adj[XIDX(w * 16 + ml, kk)];
#pragma unroll
    for (int nt = 0; nt < 4; nt++) {
      bf16x8 bh = *(const bf16x8*)&Bh[XIDX(nt * 16 + ml, kk)];
      l[nt] = MFMA(aa, bh, l[nt]);
    }
  }
  int r0 = w * 16 + kq * 4;
#pragma unroll
  for (int nt = 0; nt < 4; nt++) {
    int c = nt * 16 + ml;
    u16 hh[4], ll[4];
#pragma unroll
    for (int i = 0; i < 4; i++) {
      split2(l[nt][i] * scale, hh[i], ll[i]);
      NMh[XIDX(r0 + i, c)] = hh[i];
      NMl[XIDX(r0 + i, c)] = ll[i];
    }
    if (oCh) {
      s16x4 vh;
#pragma unroll
      for (int i = 0; i < 4; i++) vh[i] = (short)hh[i];
      *(s16x4*)&oCh[XIDX(c, r0)] = vh;
    }
  }
}

// acc += W[:, k0..k0+63] (fp32, split in-reg; optional fold subtrahend) @ X
__device__ __forceinline__ void yacc_k64(const float* wrow, const float* wfold,
                                         int w, int ml, int kq, const u16* NMh,
                                         const u16* NMl, f32x4 (&acc)[4]) {
#pragma unroll
  for (int kt = 0; kt < 2; kt++) {
    int c = kt * 32 + kq * 8;
    bf16x8 ah, al;
    if (wfold) load_split8_sub(wrow + c, wfold + c, ah, al);
    else load_split8(wrow + c, ah, al);
#pragma unroll
    for (int nt = 0; nt < 4; nt++) {
      bf16x8 bh = *(const bf16x8*)&NMh[XIDX(nt * 16 + ml, c)];
      bf16x8 bl = *(const bf16x8*)&NMl[XIDX(nt * 16 + ml, c)];
      acc[nt] = MFMA(ah, bh, acc[nt]);
      acc[nt] = MFMA(al, bh, acc[nt]);
      acc[nt] = MFMA(ah, bl, acc[nt]);
    }
  }
}

// ---------------------------------------------------------------------------
// Layer bodies as FORCE-INLINED free functions (no lambdas -> no outlining ->
// y arrays stay in VGPRs).
// ---------------------------------------------------------------------------
__device__ __forceinline__ void cheb1_graph(
    const float* __restrict__ feat, const int* __restrict__ src,
    const float* __restrict__ c1w, const float* __restrict__ c1b, int g,
    f32x4 (&y)[4], u16* NMh, u16* NMl, USh& U, int t, int lane, int w, int ml,
    int kq, int c0) {
  __syncthreads();
  {  // stage X0 = feat (node t>>2, ch (t&3)*4..+3); CM hi into U.ch.C0h
    int n = t >> 2, cc0 = (t & 3) * 4;
    float4 v = *(const float4*)(feat + (size_t)(g * 64 + n) * 16 + cc0);
    u16 hh[4], ll[4];
    split2(v.x, hh[0], ll[0]); split2(v.y, hh[1], ll[1]);
    split2(v.z, hh[2], ll[2]); split2(v.w, hh[3], ll[3]);
    s16x4 vh, vl;
#pragma unroll
    for (int i = 0; i < 4; i++) { vh[i] = (short)hh[i]; vl[i] = (short)ll[i]; }
    *(s16x4*)&NMh[XIDX(n, cc0)] = vh;
    *(s16x4*)&NMl[XIDX(n, cc0)] = vl;
#pragma unroll
    for (int i = 0; i < 4; i++) U.ch.C0h[XIDX(cc0 + i, n)] = (u16)hh[i];
  }
  if (w == 0) {
    bf16x8 z = {0, 0, 0, 0, 0, 0, 0, 0};
    *(bf16x8*)&NMh[XIDX(lane, 48)] = z;
    *(bf16x8*)&NMh[XIDX(lane, 56)] = z;
  } else if (w == 1) {
    bf16x8 z = {0, 0, 0, 0, 0, 0, 0, 0};
    *(bf16x8*)&NMl[XIDX(lane, 48)] = z;
    *(bf16x8*)&NMl[XIDX(lane, 56)] = z;
  } else if (w == 3) {
    build_adj(src, g, lane, U.ch.Adj);
  }
  __syncthreads();
  {  // lap1: X1 (chs 0..15) -> NM cols 16..31 (hi/lo) + CM rows 16..31 (hi)
    f32x4 l = {0.f, 0.f, 0.f, 0.f};
#pragma unroll
    for (int kt = 0; kt < 2; kt++) {
      int kk = kt * 32 + kq * 8;
      bf16x8 aa = *(const bf16x8*)&U.ch.Adj[XIDX(w * 16 + ml, kk)];
      bf16x8 bh = *(const bf16x8*)&U.ch.C0h[XIDX(ml, kk)];
      l = MFMA(aa, bh, l);
    }
    int r0 = w * 16 + kq * 4;
    u16 hh[4], ll[4];
#pragma unroll
    for (int i = 0; i < 4; i++) {
      split2(l[i] * (-C1), hh[i], ll[i]);
      NMh[XIDX(r0 + i, 16 + ml)] = hh[i];
      NMl[XIDX(r0 + i, 16 + ml)] = ll[i];
    }
    s16x4 vh;
#pragma unroll
    for (int i = 0; i < 4; i++) vh[i] = (short)hh[i];
    *(s16x4*)&U.ch.C0h[XIDX(16 + ml, r0)] = vh;
  }
  __syncthreads();
  {  // lap2: Z2 = -2C1*Adj*X1 -> NM cols 32..47
    f32x4 l = {0.f, 0.f, 0.f, 0.f};
#pragma unroll
    for (int kt = 0; kt < 2; kt++) {
      int kk = kt * 32 + kq * 8;
      bf16x8 aa = *(const bf16x8*)&U.ch.Adj[XIDX(w * 16 + ml, kk)];
      bf16x8 bh = *(const bf16x8*)&U.ch.C0h[XIDX(16 + ml, kk)];
      l = MFMA(aa, bh, l);
    }
    int r0 = w * 16 + kq * 4;
#pragma unroll
    for (int i = 0; i < 4; i++) {
      u16 hh, ll;
      split2(l[i] * (-2.0f * C1), hh, ll);
      NMh[XIDX(r0 + i, 32 + ml)] = hh;
      NMl[XIDX(r0 + i, 32 + ml)] = ll;
    }
  }
  __syncthreads();
  {  // Y = Xcat @ Wfold^T (K=64, fp32 W with in-reg fold/split)
    f32x4 acc[4];
#pragma unroll
    for (int nt = 0; nt < 4; nt++) acc[nt] = (f32x4){0.f, 0.f, 0.f, 0.f};
    const float* wr = c1w + (size_t)(w * 16 + ml) * 48;
#pragma unroll
    for (int kt = 0; kt < 2; kt++) {
      int c = kt * 32 + kq * 8;
      float vv[8];
      if (c < 16) {
        float4 a0 = *(const float4*)(wr + c), a1 = *(const float4*)(wr + c + 4);
        float4 b0 = *(const float4*)(wr + 32 + c),
               b1 = *(const float4*)(wr + 32 + c + 4);
        vv[0] = a0.x - b0.x; vv[1] = a0.y - b0.y; vv[2] = a0.z - b0.z;
        vv[3] = a0.w - b0.w; vv[4] = a1.x - b1.x; vv[5] = a1.y - b1.y;
        vv[6] = a1.z - b1.z; vv[7] = a1.w - b1.w;
      } else if (c < 48) {
        float4 a0 = *(const float4*)(wr + c), a1 = *(const float4*)(wr + c + 4);
        vv[0] = a0.x; vv[1] = a0.y; vv[2] = a0.z; vv[3] = a0.w;
        vv[4] = a1.x; vv[5] = a1.y; vv[6] = a1.z; vv[7] = a1.w;
      } else {
#pragma unroll
        for (int j = 0; j < 8; j++) vv[j] = 0.f;
      }
      bf16x8 ah, al;
#pragma unroll
      for (int j = 0; j < 8; j++) {
        u16 hh, ll; split2(vv[j], hh, ll);
        ah[j] = (short)hh; al[j] = (short)ll;
      }
#pragma unroll
      for (int nt = 0; nt < 4; nt++) {
        bf16x8 bh = *(const bf16x8*)&NMh[XIDX(nt * 16 + ml, c)];
        bf16x8 bl = *(const bf16x8*)&NMl[XIDX(nt * 16 + ml, c)];
        acc[nt] = MFMA(ah, bh, acc[nt]);
        acc[nt] = MFMA(al, bh, acc[nt]);
        acc[nt] = MFMA(ah, bl, acc[nt]);
      }
    }
    float4 bb = *(const float4*)(c1b + c0);
#pragma unroll
    for (int nt = 0; nt < 4; nt++) {
      y[nt][0] = acc[nt][0] + bb.x; y[nt][1] = acc[nt][1] + bb.y;
      y[nt][2] = acc[nt][2] + bb.z; y[nt][3] = acc[nt][3] + bb.w;
    }
  }
}

__device__ __forceinline__ void econv_graph(
    const int* __restrict__ src, const float* __restrict__ gam,
    const float* __restrict__ bet, const float* __restrict__ tw,
    const float* __restrict__ tb, const float* __restrict__ pw,
    const float* __restrict__ pb, int g, f32x4 (&y)[4], u16* NMh, u16* NMl,
    USh& U, const float* sStats, int t, int w, int ml, int kq, int c0) {
  __syncthreads();
  stage_from_regs(y, sStats, gam, bet, w, ml, kq, NMh, NMl, nullptr);
  {
    int4 v = ((const int4*)(src + (size_t)g * 1024))[t];
    int b0 = g * 64;
    U.ec.sW[t] = (unsigned)(v.x - b0) | ((unsigned)(v.y - b0) << 8) |
                 ((unsigned)(v.z - b0) << 16) | ((unsigned)(v.w - b0) << 24);
  }
  __syncthreads();
  f32x4 T[4], P[4];
#pragma unroll
  for (int nt = 0; nt < 4; nt++) {
    T[nt] = (f32x4){0.f, 0.f, 0.f, 0.f};
    P[nt] = (f32x4){0.f, 0.f, 0.f, 0.f};
  }
  const float* twr = tw + (size_t)(w * 16 + ml) * 64;
  const float* pwr = pw + (size_t)(w * 16 + ml) * 64;
#pragma unroll
  for (int kt = 0; kt < 2; kt++) {
    int c = kt * 32 + kq * 8;
    bf16x8 ath, atl, aph, apl;
    load_split8(twr + c, ath, atl);
    load_split8(pwr + c, aph, apl);
#pragma unroll
    for (int nt = 0; nt < 4; nt++) {
      bf16x8 bh = *(const bf16x8*)&NMh[XIDX(nt * 16 + ml, c)];
      bf16x8 bl = *(const bf16x8*)&NMl[XIDX(nt * 16 + ml, c)];
      T[nt] = MFMA(ath, bh, T[nt]); T[nt] = MFMA(atl, bh, T[nt]);
      T[nt] = MFMA(ath, bl, T[nt]);
      P[nt] = MFMA(aph, bh, P[nt]); P[nt] = MFMA(apl, bh, P[nt]);
      P[nt] = MFMA(aph, bl, P[nt]);
    }
  }
#pragma unroll
  for (int nt = 0; nt < 4; nt++) {
    int n = nt * 16 + ml;
    *(float4*)&U.ec.Tf[n * 68 + c0] =
        make_float4(T[nt][0], T[nt][1], T[nt][2], T[nt][3]);
  }
  float4 tbv = *(const float4*)(tb + c0);
  float4 pbv = *(const float4*)(pb + c0);
#pragma unroll
  for (int nt = 0; nt < 4; nt++) {
    int n = nt * 16 + ml;
    unsigned w0 = U.ec.sW[n * 4], w1 = U.ec.sW[n * 4 + 1],
             w2v = U.ec.sW[n * 4 + 2], w3v = U.ec.sW[n * 4 + 3];
    float4 mn = {3.4e38f, 3.4e38f, 3.4e38f, 3.4e38f};
#pragma unroll
    for (int e = 0; e < 16; e++) {
      unsigned wd = (e < 4) ? w0 : (e < 8) ? w1 : (e < 12) ? w2v : w3v;
      int s = (wd >> ((e & 3) * 8)) & 255;
      float4 tv = *(const float4*)&U.ec.Tf[s * 68 + c0];
      mn.x = fminf(mn.x, tv.x); mn.y = fminf(mn.y, tv.y);
      mn.z = fminf(mn.z, tv.z); mn.w = fminf(mn.w, tv.w);
    }
    y[nt][0] = T[nt][0] + P[nt][0] + tbv.x + pbv.x - mn.x;
    y[nt][1] = T[nt][1] + P[nt][1] + tbv.y + pbv.y - mn.y;
    y[nt][2] = T[nt][2] + P[nt][2] + tbv.z + pbv.z - mn.z;
    y[nt][3] = T[nt][3] + P[nt][3] + tbv.w + pbv.w - mn.w;
  }
}

__device__ __forceinline__ void cheb64_graph(
    const int* __restrict__ src, const float* __restrict__ gam,
    const float* __restrict__ bet, const float* __restrict__ W,
    const float* __restrict__ bias, int g, f32x4 (&y)[4], u16* NMh, u16* NMl,
    USh& U, const float* sStats, int lane, int w, int ml, int kq, int c0) {
  __syncthreads();
  stage_from_regs(y, sStats, gam, bet, w, ml, kq, NMh, NMl, U.ch.C0h);
  if (w == 3) build_adj(src, g, lane, U.ch.Adj);
  __syncthreads();
  f32x4 acc[4];
#pragma unroll
  for (int nt = 0; nt < 4; nt++) acc[nt] = (f32x4){0.f, 0.f, 0.f, 0.f};
  const float* wr = W + (size_t)(w * 16 + ml) * 192;
  yacc_k64(wr, wr + 128, w, ml, kq, NMh, NMl, acc);  // W0-W2 fold @ X0
  __syncthreads();
  lap_step(U.ch.C0h, U.ch.Adj, -C1, w, ml, kq, NMh, NMl, U.ch.C1h);
  __syncthreads();
  yacc_k64(wr + 64, nullptr, w, ml, kq, NMh, NMl, acc);  // W1 @ X1
  __syncthreads();
  lap_step(U.ch.C1h, U.ch.Adj, -2.0f * C1, w, ml, kq, NMh, NMl, nullptr);
  __syncthreads();
  yacc_k64(wr + 128, nullptr, w, ml, kq, NMh, NMl, acc);  // W2 @ Z2
  float4 bb = *(const float4*)(bias + c0);
#pragma unroll
  for (int nt = 0; nt < 4; nt++) {
    y[nt][0] = acc[nt][0] + bb.x; y[nt][1] = acc[nt][1] + bb.y;
    y[nt][2] = acc[nt][2] + bb.z; y[nt][3] = acc[nt][3] + bb.w;
  }
}

__device__ __forceinline__ void stats_round(
    int L, const f32x4 (&yA)[4], const f32x4 (&yB)[4], float* part,
    float* gstats, unsigned* bar, float* sStats, float* sRed, int blk, int t,
    int ml, int c0) {
  float s1[4] = {0.f, 0.f, 0.f, 0.f}, s2[4] = {0.f, 0.f, 0.f, 0.f};
#pragma unroll
  for (int nt = 0; nt < 4; nt++) {
#pragma unroll
    for (int i = 0; i < 4; i++) {
      float a = yA[nt][i], b = yB[nt][i];
      s1[i] += a + b;
      s2[i] += a * a + b * b;
    }
  }
#pragma unroll
  for (int i = 0; i < 4; i++) {
#pragma unroll
    for (int off = 1; off < 16; off <<= 1) {
      s1[i] += __shfl_xor(s1[i], off, 64);
      s2[i] += __shfl_xor(s2[i], off, 64);
    }
  }
  if (ml == 0) {
    float* prow = part + (size_t)blk * 128;
#pragma unroll
    for (int i = 0; i < 4; i++) {
      cstore(prow + c0 + i, s1[i]);
      cstore(prow + 64 + c0 + i, s2[i]);
    }
  }
  gbarrier(bar, L * 2, blk);
  if (blk < 8) {
    int cc = t & 15, rg = t >> 4;
    const float* pp = part + (size_t)(rg * 32) * 128 + blk * 16 + cc;
    float a = 0.f;
#pragma unroll 8
    for (int r = 0; r < 32; r++) a += cload(pp + (size_t)r * 128);
    sRed[t] = a;
    __syncthreads();
    if (t < 16) {
      float s = 0.f;
#pragma unroll
      for (int k = 0; k < 16; k++) s += sRed[k * 16 + t];
      cstore(gstats + L * 128 + blk * 16 + t, s);
    }
  }
  gbarrier(bar, L * 2 + 1, blk);
  if (t < 128) sStats[t] = cload(gstats + L * 128 + t);
  __syncthreads();
}

__device__ __forceinline__ void pool_graph(const float* __restrict__ bn3g,
                                           const float* __restrict__ bn3b,
                                           float* __restrict__ out, int g,
                                           const f32x4 (&y)[4],
                                           const float* sStats, int ml, int c0) {
  float sc[4], sh[4];
  bn_coeffs(sStats, bn3g, bn3b, c0, sc, sh);
  float vs[4] = {0.f, 0.f, 0.f, 0.f};
#pragma unroll
  for (int nt = 0; nt < 4; nt++)
#pragma unroll
    for (int i = 0; i < 4; i++)
      vs[i] += fmaxf(fmaf(sc[i], y[nt][i], sh[i]), 0.f);
#pragma unroll
  for (int i = 0; i < 4; i++)
#pragma unroll
    for (int off = 1; off < 16; off <<= 1) vs[i] += __shfl_xor(vs[i], off, 64);
  if (ml == 0) {
    const float r64 = 1.0f / 64.0f;
    *(float4*)(out + (size_t)g * 64 + c0) =
        make_float4(vs[0] * r64, vs[1] * r64, vs[2] * r64, vs[3] * r64);
  }
}

// ---------------------------------------------------------------------------
__global__ __launch_bounds__(256, 3) void k_fused(
    const float* __restrict__ feat, const int* __restrict__ src,
    const float* __restrict__ c1w, const float* __restrict__ c1b,
    const float* __restrict__ bn1g, const float* __restrict__ bn1b,
    const float* __restrict__ e1tw, const float* __restrict__ e1tb,
    const float* __restrict__ e1pw, const float* __restrict__ e1pb,
    const float* __restrict__ bne1g, const float* __restrict__ bne1b,
    const float* __restrict__ c2w, const float* __restrict__ c2b,
    const float* __restrict__ bn2g, const float* __restrict__ bn2b,
    const float* __restrict__ e2tw, const float* __restrict__ e2tb,
    const float* __restrict__ e2pw, const float* __restrict__ e2pb,
    const float* __restrict__ bne2g, const float* __restrict__ bne2b,
    const float* __restrict__ c3w, const float* __restrict__ c3b,
    const float* __restrict__ bn3g, const float* __restrict__ bn3b,
    float* __restrict__ out, float* __restrict__ part,
    float* __restrict__ gstats, unsigned* __restrict__ bar) {
  __shared__ __align__(16) u16 NMh[4096];
  __shared__ __align__(16) u16 NMl[4096];
  __shared__ __align__(16) USh U;
  __shared__ float sStats[128];
  __shared__ float sRed[256];

  const int t = threadIdx.x, blk = blockIdx.x;
  const int lane = t & 63;
  const int w = __builtin_amdgcn_readfirstlane(t >> 6);
  const int ml = lane & 15, kq = lane >> 4;
  const int c0 = w * 16 + kq * 4;

  f32x4 yA[4], yB[4];   // persistent activations — VGPR-resident

  cheb1_graph(feat, src, c1w, c1b, blk * 2, yA, NMh, NMl, U, t, lane, w, ml, kq, c0);
  cheb1_graph(feat, src, c1w, c1b, blk * 2 + 1, yB, NMh, NMl, U, t, lane, w, ml, kq, c0);
  stats_round(0, yA, yB, part, gstats, bar, sStats, sRed, blk, t, ml, c0);

  econv_graph(src, bn1g, bn1b, e1tw, e1tb, e1pw, e1pb, blk * 2, yA, NMh, NMl, U, sStats, t, w, ml, kq, c0);
  econv_graph(src, bn1g, bn1b, e1tw, e1tb, e1pw, e1pb, blk * 2 + 1, yB, NMh, NMl, U, sStats, t, w, ml, kq, c0);
  stats_round(1, yA, yB, part, gstats, bar, sStats, sRed, blk, t, ml, c0);

  cheb64_graph(src, bne1g, bne1b, c2w, c2b, blk * 2, yA, NMh, NMl, U, sStats, lane, w, ml, kq, c0);
  cheb64_graph(src, bne1g, bne1b, c2w, c2b, blk * 2 + 1, yB, NMh, NMl, U, sStats, lane, w, ml, kq, c0);
  stats_round(2, yA, yB, part, gstats, bar, sStats, sRed, blk, t, ml, c0);

  econv_graph(src, bn2g, bn2b, e2tw, e2tb, e2pw, e2pb, blk * 2, yA, NMh, NMl, U, sStats, t, w, ml, kq, c0);
  econv_graph(src, bn2g, bn2b, e2tw, e2tb, e2pw, e2pb, blk * 2 + 1, yB, NMh, NMl, U, sStats, t, w, ml, kq, c0);
  stats_round(3, yA, yB, part, gstats, bar, sStats, sRed, blk, t, ml, c0);

  cheb64_graph(src, bne2g, bne2b, c3w, c3b, blk * 2, yA, NMh, NMl, U, sStats, lane, w, ml, kq, c0);
  cheb64_graph(src, bne2g, bne2b, c3w, c3b, blk * 2 + 1, yB, NMh, NMl, U, sStats, lane, w, ml, kq, c0);
  stats_round(4, yA, yB, part, gstats, bar, sStats, sRed, blk, t, ml, c0);

  pool_graph(bn3g, bn3b, out, blk * 2, yA, sStats, ml, c0);
  pool_graph(bn3g, bn3b, out, blk * 2 + 1, yB, sStats, ml, c0);
}

// ---------------------------------------------------------------------------
extern "C" void kernel_launch(void* const* d_in, const int* in_sizes, int n_in,
                              void* d_out, int out_size, void* d_ws,
                              size_t ws_size, hipStream_t stream) {
  const float* feat = (const float*)d_in[0];
  const int* src = (const int*)d_in[1];
  const float* cheb1_w = (const float*)d_in[4];
  const float* cheb1_b = (const float*)d_in[5];
  const float* bn1_g = (const float*)d_in[6];
  const float* bn1_b = (const float*)d_in[7];
  const float* e1_tw = (const float*)d_in[8];
  const float* e1_tb = (const float*)d_in[9];
  const float* e1_pw = (const float*)d_in[10];
  const float* e1_pb = (const float*)d_in[11];
  const float* bne1_g = (const float*)d_in[12];
  const float* bne1_b = (const float*)d_in[13];
  const float* cheb2_w = (const float*)d_in[14];
  const float* cheb2_b = (const float*)d_in[15];
  const float* bn2_g = (const float*)d_in[16];
  const float* bn2_b = (const float*)d_in[17];
  const float* e2_tw = (const float*)d_in[18];
  const float* e2_tb = (const float*)d_in[19];
  const float* e2_pw = (const float*)d_in[20];
  const float* e2_pb = (const float*)d_in[21];
  const float* bne2_g = (const float*)d_in[22];
  const float* bne2_b = (const float*)d_in[23];
  const float* cheb3_w = (const float*)d_in[24];
  const float* cheb3_b = (const float*)d_in[25];
  const float* bn3_g = (const float*)d_in[26];
  const float* bn3_b = (const float*)d_in[27];

  float* part = (float*)d_ws;                       // 512 x 128
  float* gstats = part + 512 * 128;                 // 5 x 128
  unsigned* bar = (unsigned*)(gstats + 5 * 128);    // 10 slots x 640 B

  hipMemsetAsync(bar, 0, 8192, stream);

  k_fused<<<512, 256, 0, stream>>>(
      feat, src, cheb1_w, cheb1_b, bn1_g, bn1_b, e1_tw, e1_tb, e1_pw, e1_pb,
      bne1_g, bne1_b, cheb2_w, cheb2_b, bn2_g, bn2_b, e2_tw, e2_tb, e2_pw,
      e2_pb, bne2_g, bne2_b, cheb3_w, cheb3_b, bn3_g, bn3_b, (float*)d_out,
      part, gstats, bar);
}

// Round 8
// 240.533 us; speedup vs baseline: 1.9768x; 1.0036x over previous
//
#include <hip/hip_runtime.h>

#define EPSF 1e-5f
#define C1 0.0625f

typedef short bf16x8 __attribute__((ext_vector_type(8)));
typedef short s16x4 __attribute__((ext_vector_type(4)));
typedef float f32x4 __attribute__((ext_vector_type(4)));
typedef unsigned short u16;

#define MFMA(a, b, c) __builtin_amdgcn_mfma_f32_16x16x32_bf16(a, b, c, 0, 0, 0)

// coherent (cross-XCD) scalar access helpers — lower to global_* with sc1.
__device__ __forceinline__ void cstore(float* p, float v) {
  __hip_atomic_store(p, v, __ATOMIC_RELAXED, __HIP_MEMORY_SCOPE_AGENT);
}
__device__ __forceinline__ float cload(const float* p) {
  return __hip_atomic_load(p, __ATOMIC_RELAXED, __HIP_MEMORY_SCOPE_AGENT);
}

__device__ __forceinline__ u16 f2bf(float x) {
  union { float f; unsigned u; } v; v.f = x;
  unsigned r = v.u + 0x7fffu + ((v.u >> 16) & 1u);
  return (u16)(r >> 16);
}
__device__ __forceinline__ float bf2f(u16 h) {
  union { float f; unsigned u; } v; v.u = ((unsigned)h) << 16; return v.f;
}
__device__ __forceinline__ void split2(float x, u16& h, u16& l) {
  h = f2bf(x); l = f2bf(x - bf2f(h));
}
// swizzled index into a 64x64 u16 LDS tile: 16B granules XOR'd by row&7
__device__ __forceinline__ int XIDX(int r, int c) {
  return r * 64 + ((((c >> 3) ^ (r & 7)) << 3) | (c & 7));
}
__device__ __forceinline__ f32x4 addb(f32x4 a, float4 b) {
  f32x4 r; r[0] = a[0] + b.x; r[1] = a[1] + b.y;
  r[2] = a[2] + b.z; r[3] = a[3] + b.w; return r;
}

// LDS overlay: cheb layers need C0h/C1h/Adj; econv needs Tf + sW.
struct ChebSh { u16 C0h[4096]; u16 C1h[4096]; u16 Adj[4096]; };
struct EcSh { float Tf[64 * 68]; unsigned sW[256]; };
union USh { ChebSh ch; EcSh ec; };

// ---------------------------------------------------------------------------
__device__ __forceinline__ void gbarrier(unsigned* bar, int slot, int blk) {
  __syncthreads();
  if (threadIdx.x == 0) {
    __builtin_amdgcn_s_waitcnt(0);
    unsigned* base = bar + slot * 160;
    unsigned old = atomicAdd(base + (blk & 7) * 16, 1u);
    if (old == 63u) atomicAdd(base + 128, 1u);
    while (__hip_atomic_load(base + 128, __ATOMIC_RELAXED,
                             __HIP_MEMORY_SCOPE_AGENT) < 8u)
      __builtin_amdgcn_s_sleep(4);
  }
  __syncthreads();
}

// Build local adjacency multiplicity matrix (bf16 exact ints <=16), wave 3.
__device__ __forceinline__ void build_adj(const int* __restrict__ src, int g,
                                          int r, u16* Adj) {
  bf16x8 z = {0, 0, 0, 0, 0, 0, 0, 0};
#pragma unroll
  for (int q = 0; q < 8; q++) *(bf16x8*)&Adj[r * 64 + q * 8] = z;
  const int4* s4 = (const int4*)(src + (size_t)g * 1024 + (size_t)r * 16);
  int4 a0 = s4[0], a1 = s4[1], a2 = s4[2], a3 = s4[3];
  int b0 = g * 64;
  int ss[16] = {a0.x - b0, a0.y - b0, a0.z - b0, a0.w - b0,
                a1.x - b0, a1.y - b0, a1.z - b0, a1.w - b0,
                a2.x - b0, a2.y - b0, a2.z - b0, a2.w - b0,
                a3.x - b0, a3.y - b0, a3.z - b0, a3.w - b0};
#pragma unroll
  for (int e = 0; e < 16; e++) {
    int idx = XIDX(r, ss[e]);
    Adj[idx] = f2bf(bf2f(Adj[idx]) + 1.0f);
  }
}

// load 8 fp32 weights, split to bf16 hi/lo frags
__device__ __forceinline__ void load_split8(const float* p, bf16x8& h, bf16x8& l) {
  float4 v0 = *(const float4*)p;
  float4 v1 = *(const float4*)(p + 4);
  float vv[8] = {v0.x, v0.y, v0.z, v0.w, v1.x, v1.y, v1.z, v1.w};
#pragma unroll
  for (int j = 0; j < 8; j++) {
    u16 hh, ll; split2(vv[j], hh, ll);
    h[j] = (short)hh; l[j] = (short)ll;
  }
}
__device__ __forceinline__ void load_split8_sub(const float* p, const float* q,
                                                bf16x8& h, bf16x8& l) {
  float4 v0 = *(const float4*)p;
  float4 v1 = *(const float4*)(p + 4);
  float4 u0 = *(const float4*)q;
  float4 u1 = *(const float4*)(q + 4);
  float vv[8] = {v0.x - u0.x, v0.y - u0.y, v0.z - u0.z, v0.w - u0.w,
                 v1.x - u1.x, v1.y - u1.y, v1.z - u1.z, v1.w - u1.w};
#pragma unroll
  for (int j = 0; j < 8; j++) {
    u16 hh, ll; split2(vv[j], hh, ll);
    h[j] = (short)hh; l[j] = (short)ll;
  }
}

__device__ __forceinline__ void bn_coeffs(const float* sStats, const float* gam,
                                          const float* bet, int c0, float* sc,
                                          float* sh) {
  const float inv = 1.0f / 65536.0f;
#pragma unroll
  for (int i = 0; i < 4; i++) {
    float m1 = sStats[c0 + i] * inv;
    float var = fmaf(sStats[64 + c0 + i], inv, -m1 * m1);
    float s = gam[c0 + i] * rsqrtf(var + EPSF);
    sc[i] = s;
    sh[i] = fmaf(-m1, s, bet[c0 + i]);
  }
}

// BN+ReLU y (by VALUE, 4 scalars), stage into NM (hi/lo) + optional CM(hi).
__device__ __forceinline__ void stage_bn4(f32x4 y0, f32x4 y1, f32x4 y2,
                                          f32x4 y3, const float* sStats,
                                          const float* gam, const float* bet,
                                          int w, int ml, int kq, u16* NMh,
                                          u16* NMl, u16* CMh) {
  int c0 = w * 16 + kq * 4;
  float sc[4], sh[4];
  bn_coeffs(sStats, gam, bet, c0, sc, sh);
  f32x4 yy[4] = {y0, y1, y2, y3};   // local, straight-line, const-indexed
#pragma unroll
  for (int nt = 0; nt < 4; nt++) {
    int n = nt * 16 + ml;
    u16 hh[4], ll[4];
#pragma unroll
    for (int i = 0; i < 4; i++) {
      float h = fmaxf(fmaf(sc[i], yy[nt][i], sh[i]), 0.f);
      split2(h, hh[i], ll[i]);
    }
    s16x4 vh, vl;
#pragma unroll
    for (int i = 0; i < 4; i++) { vh[i] = (short)hh[i]; vl[i] = (short)ll[i]; }
    *(s16x4*)&NMh[XIDX(n, c0)] = vh;
    *(s16x4*)&NMl[XIDX(n, c0)] = vl;
    if (CMh) {
#pragma unroll
      for (int i = 0; i < 4; i++) CMh[XIDX(c0 + i, n)] = (u16)hh[i];
    }
  }
}

// X_next = scale * Adj * X (X read ch-major hi-only); out -> NM (hi/lo) + opt CM
__device__ __forceinline__ void lap_step(const u16* Bh, const u16* Adj,
                                         float scale, int w, int ml, int kq,
                                         u16* NMh, u16* NMl, u16* oCh) {
  f32x4 l[4];
#pragma unroll
  for (int nt = 0; nt < 4; nt++) l[nt] = (f32x4){0.f, 0.f, 0.f, 0.f};
#pragma unroll
  for (int kt = 0; kt < 2; kt++) {
    int kk = kt * 32 + kq * 8;
    bf16x8 aa = *(const bf16x8*)&Adj[XIDX(w * 16 + ml, kk)];
#pragma unroll
    for (int nt = 0; nt < 4; nt++) {
      bf16x8 bh = *(const bf16x8*)&Bh[XIDX(nt * 16 + ml, kk)];
      l[nt] = MFMA(aa, bh, l[nt]);
    }
  }
  int r0 = w * 16 + kq * 4;
#pragma unroll
  for (int nt = 0; nt < 4; nt++) {
    int c = nt * 16 + ml;
    u16 hh[4], ll[4];
#pragma unroll
    for (int i = 0; i < 4; i++) {
      split2(l[nt][i] * scale, hh[i], ll[i]);
      NMh[XIDX(r0 + i, c)] = hh[i];
      NMl[XIDX(r0 + i, c)] = ll[i];
    }
    if (oCh) {
      s16x4 vh;
#pragma unroll
      for (int i = 0; i < 4; i++) vh[i] = (short)hh[i];
      *(s16x4*)&oCh[XIDX(c, r0)] = vh;
    }
  }
}

// acc += W[:, k0..k0+63] @ X; accumulators as 4 SCALAR refs (SROA-safe).
__device__ __forceinline__ void yacc_k64(const float* wrow, const float* wfold,
                                         int w, int ml, int kq, const u16* NMh,
                                         const u16* NMl, f32x4& a0, f32x4& a1,
                                         f32x4& a2, f32x4& a3) {
  f32x4 aa[4] = {a0, a1, a2, a3};
#pragma unroll
  for (int kt = 0; kt < 2; kt++) {
    int c = kt * 32 + kq * 8;
    bf16x8 ah, al;
    if (wfold) load_split8_sub(wrow + c, wfold + c, ah, al);
    else load_split8(wrow + c, ah, al);
#pragma unroll
    for (int nt = 0; nt < 4; nt++) {
      bf16x8 bh = *(const bf16x8*)&NMh[XIDX(nt * 16 + ml, c)];
      bf16x8 bl = *(const bf16x8*)&NMl[XIDX(nt * 16 + ml, c)];
      aa[nt] = MFMA(ah, bh, aa[nt]);
      aa[nt] = MFMA(al, bh, aa[nt]);
      aa[nt] = MFMA(ah, bl, aa[nt]);
    }
  }
  a0 = aa[0]; a1 = aa[1]; a2 = aa[2]; a3 = aa[3];
}

// ---------------------------------------------------------------------------
// Layer bodies — all cross-function state is SCALAR f32x4 (ref or value).
// ---------------------------------------------------------------------------
__device__ __forceinline__ void cheb1_graph(
    const float* __restrict__ feat, const int* __restrict__ src,
    const float* __restrict__ c1w, const float* __restrict__ c1b, int g,
    f32x4& o0, f32x4& o1, f32x4& o2, f32x4& o3, u16* NMh, u16* NMl, USh& U,
    int t, int lane, int w, int ml, int kq, int c0) {
  __syncthreads();
  {  // stage X0 = feat (node t>>2, ch (t&3)*4..+3); CM hi into U.ch.C0h
    int n = t >> 2, cc0 = (t & 3) * 4;
    float4 v = *(const float4*)(feat + (size_t)(g * 64 + n) * 16 + cc0);
    u16 hh[4], ll[4];
    split2(v.x, hh[0], ll[0]); split2(v.y, hh[1], ll[1]);
    split2(v.z, hh[2], ll[2]); split2(v.w, hh[3], ll[3]);
    s16x4 vh, vl;
#pragma unroll
    for (int i = 0; i < 4; i++) { vh[i] = (short)hh[i]; vl[i] = (short)ll[i]; }
    *(s16x4*)&NMh[XIDX(n, cc0)] = vh;
    *(s16x4*)&NMl[XIDX(n, cc0)] = vl;
#pragma unroll
    for (int i = 0; i < 4; i++) U.ch.C0h[XIDX(cc0 + i, n)] = (u16)hh[i];
  }
  if (w == 0) {
    bf16x8 z = {0, 0, 0, 0, 0, 0, 0, 0};
    *(bf16x8*)&NMh[XIDX(lane, 48)] = z;
    *(bf16x8*)&NMh[XIDX(lane, 56)] = z;
  } else if (w == 1) {
    bf16x8 z = {0, 0, 0, 0, 0, 0, 0, 0};
    *(bf16x8*)&NMl[XIDX(lane, 48)] = z;
    *(bf16x8*)&NMl[XIDX(lane, 56)] = z;
  } else if (w == 3) {
    build_adj(src, g, lane, U.ch.Adj);
  }
  __syncthreads();
  {  // lap1: X1 (chs 0..15) -> NM cols 16..31 (hi/lo) + CM rows 16..31 (hi)
    f32x4 l = {0.f, 0.f, 0.f, 0.f};
#pragma unroll
    for (int kt = 0; kt < 2; kt++) {
      int kk = kt * 32 + kq * 8;
      bf16x8 aa = *(const bf16x8*)&U.ch.Adj[XIDX(w * 16 + ml, kk)];
      bf16x8 bh = *(const bf16x8*)&U.ch.C0h[XIDX(ml, kk)];
      l = MFMA(aa, bh, l);
    }
    int r0 = w * 16 + kq * 4;
    u16 hh[4], ll[4];
#pragma unroll
    for (int i = 0; i < 4; i++) {
      split2(l[i] * (-C1), hh[i], ll[i]);
      NMh[XIDX(r0 + i, 16 + ml)] = hh[i];
      NMl[XIDX(r0 + i, 16 + ml)] = ll[i];
    }
    s16x4 vh;
#pragma unroll
    for (int i = 0; i < 4; i++) vh[i] = (short)hh[i];
    *(s16x4*)&U.ch.C0h[XIDX(16 + ml, r0)] = vh;
  }
  __syncthreads();
  {  // lap2: Z2 = -2C1*Adj*X1 -> NM cols 32..47
    f32x4 l = {0.f, 0.f, 0.f, 0.f};
#pragma unroll
    for (int kt = 0; kt < 2; kt++) {
      int kk = kt * 32 + kq * 8;
      bf16x8 aa = *(const bf16x8*)&U.ch.Adj[XIDX(w * 16 + ml, kk)];
      bf16x8 bh = *(const bf16x8*)&U.ch.C0h[XIDX(16 + ml, kk)];
      l = MFMA(aa, bh, l);
    }
    int r0 = w * 16 + kq * 4;
#pragma unroll
    for (int i = 0; i < 4; i++) {
      u16 hh, ll;
      split2(l[i] * (-2.0f * C1), hh, ll);
      NMh[XIDX(r0 + i, 32 + ml)] = hh;
      NMl[XIDX(r0 + i, 32 + ml)] = ll;
    }
  }
  __syncthreads();
  {  // Y = Xcat @ Wfold^T (K=64, fp32 W with in-reg fold/split)
    f32x4 acc[4];
#pragma unroll
    for (int nt = 0; nt < 4; nt++) acc[nt] = (f32x4){0.f, 0.f, 0.f, 0.f};
    const float* wr = c1w + (size_t)(w * 16 + ml) * 48;
#pragma unroll
    for (int kt = 0; kt < 2; kt++) {
      int c = kt * 32 + kq * 8;
      float vv[8];
      if (c < 16) {
        float4 a0 = *(const float4*)(wr + c), a1 = *(const float4*)(wr + c + 4);
        float4 b0 = *(const float4*)(wr + 32 + c),
               b1 = *(const float4*)(wr + 32 + c + 4);
        vv[0] = a0.x - b0.x; vv[1] = a0.y - b0.y; vv[2] = a0.z - b0.z;
        vv[3] = a0.w - b0.w; vv[4] = a1.x - b1.x; vv[5] = a1.y - b1.y;
        vv[6] = a1.z - b1.z; vv[7] = a1.w - b1.w;
      } else if (c < 48) {
        float4 a0 = *(const float4*)(wr + c), a1 = *(const float4*)(wr + c + 4);
        vv[0] = a0.x; vv[1] = a0.y; vv[2] = a0.z; vv[3] = a0.w;
        vv[4] = a1.x; vv[5] = a1.y; vv[6] = a1.z; vv[7] = a1.w;
      } else {
#pragma unroll
        for (int j = 0; j < 8; j++) vv[j] = 0.f;
      }
      bf16x8 ah, al;
#pragma unroll
      for (int j = 0; j < 8; j++) {
        u16 hh, ll; split2(vv[j], hh, ll);
        ah[j] = (short)hh; al[j] = (short)ll;
      }
#pragma unroll
      for (int nt = 0; nt < 4; nt++) {
        bf16x8 bh = *(const bf16x8*)&NMh[XIDX(nt * 16 + ml, c)];
        bf16x8 bl = *(const bf16x8*)&NMl[XIDX(nt * 16 + ml, c)];
        acc[nt] = MFMA(ah, bh, acc[nt]);
        acc[nt] = MFMA(al, bh, acc[nt]);
        acc[nt] = MFMA(ah, bl, acc[nt]);
      }
    }
    float4 bb = *(const float4*)(c1b + c0);
    o0 = addb(acc[0], bb); o1 = addb(acc[1], bb);
    o2 = addb(acc[2], bb); o3 = addb(acc[3], bb);
  }
}

__device__ __forceinline__ void econv_graph(
    const int* __restrict__ src, const float* __restrict__ gam,
    const float* __restrict__ bet, const float* __restrict__ tw,
    const float* __restrict__ tb, const float* __restrict__ pw,
    const float* __restrict__ pb, int g, f32x4& y0, f32x4& y1, f32x4& y2,
    f32x4& y3, u16* NMh, u16* NMl, USh& U, const float* sStats, int t, int w,
    int ml, int kq, int c0) {
  __syncthreads();
  stage_bn4(y0, y1, y2, y3, sStats, gam, bet, w, ml, kq, NMh, NMl, nullptr);
  {
    int4 v = ((const int4*)(src + (size_t)g * 1024))[t];
    int b0 = g * 64;
    U.ec.sW[t] = (unsigned)(v.x - b0) | ((unsigned)(v.y - b0) << 8) |
                 ((unsigned)(v.z - b0) << 16) | ((unsigned)(v.w - b0) << 24);
  }
  __syncthreads();
  f32x4 T[4], P[4];
#pragma unroll
  for (int nt = 0; nt < 4; nt++) {
    T[nt] = (f32x4){0.f, 0.f, 0.f, 0.f};
    P[nt] = (f32x4){0.f, 0.f, 0.f, 0.f};
  }
  const float* twr = tw + (size_t)(w * 16 + ml) * 64;
  const float* pwr = pw + (size_t)(w * 16 + ml) * 64;
#pragma unroll
  for (int kt = 0; kt < 2; kt++) {
    int c = kt * 32 + kq * 8;
    bf16x8 ath, atl, aph, apl;
    load_split8(twr + c, ath, atl);
    load_split8(pwr + c, aph, apl);
#pragma unroll
    for (int nt = 0; nt < 4; nt++) {
      bf16x8 bh = *(const bf16x8*)&NMh[XIDX(nt * 16 + ml, c)];
      bf16x8 bl = *(const bf16x8*)&NMl[XIDX(nt * 16 + ml, c)];
      T[nt] = MFMA(ath, bh, T[nt]); T[nt] = MFMA(atl, bh, T[nt]);
      T[nt] = MFMA(ath, bl, T[nt]);
      P[nt] = MFMA(aph, bh, P[nt]); P[nt] = MFMA(apl, bh, P[nt]);
      P[nt] = MFMA(aph, bl, P[nt]);
    }
  }
#pragma unroll
  for (int nt = 0; nt < 4; nt++) {
    int n = nt * 16 + ml;
    *(float4*)&U.ec.Tf[n * 68 + c0] =
        make_float4(T[nt][0], T[nt][1], T[nt][2], T[nt][3]);
  }
  float4 tbv = *(const float4*)(tb + c0);
  float4 pbv = *(const float4*)(pb + c0);
  f32x4 yo[4];
#pragma unroll
  for (int nt = 0; nt < 4; nt++) {
    int n = nt * 16 + ml;
    unsigned w0 = U.ec.sW[n * 4], w1 = U.ec.sW[n * 4 + 1],
             w2v = U.ec.sW[n * 4 + 2], w3v = U.ec.sW[n * 4 + 3];
    float4 mn = {3.4e38f, 3.4e38f, 3.4e38f, 3.4e38f};
#pragma unroll
    for (int e = 0; e < 16; e++) {
      unsigned wd = (e < 4) ? w0 : (e < 8) ? w1 : (e < 12) ? w2v : w3v;
      int s = (wd >> ((e & 3) * 8)) & 255;
      float4 tv = *(const float4*)&U.ec.Tf[s * 68 + c0];
      mn.x = fminf(mn.x, tv.x); mn.y = fminf(mn.y, tv.y);
      mn.z = fminf(mn.z, tv.z); mn.w = fminf(mn.w, tv.w);
    }
    yo[nt][0] = T[nt][0] + P[nt][0] + tbv.x + pbv.x - mn.x;
    yo[nt][1] = T[nt][1] + P[nt][1] + tbv.y + pbv.y - mn.y;
    yo[nt][2] = T[nt][2] + P[nt][2] + tbv.z + pbv.z - mn.z;
    yo[nt][3] = T[nt][3] + P[nt][3] + tbv.w + pbv.w - mn.w;
  }
  y0 = yo[0]; y1 = yo[1]; y2 = yo[2]; y3 = yo[3];
}

__device__ __forceinline__ void cheb64_graph(
    const int* __restrict__ src, const float* __restrict__ gam,
    const float* __restrict__ bet, const float* __restrict__ W,
    const float* __restrict__ bias, int g, f32x4& y0, f32x4& y1, f32x4& y2,
    f32x4& y3, u16* NMh, u16* NMl, USh& U, const float* sStats, int lane,
    int w, int ml, int kq, int c0) {
  __syncthreads();
  stage_bn4(y0, y1, y2, y3, sStats, gam, bet, w, ml, kq, NMh, NMl, U.ch.C0h);
  if (w == 3) build_adj(src, g, lane, U.ch.Adj);
  __syncthreads();
  f32x4 q0 = {0.f, 0.f, 0.f, 0.f}, q1 = {0.f, 0.f, 0.f, 0.f},
        q2 = {0.f, 0.f, 0.f, 0.f}, q3 = {0.f, 0.f, 0.f, 0.f};
  const float* wr = W + (size_t)(w * 16 + ml) * 192;
  yacc_k64(wr, wr + 128, w, ml, kq, NMh, NMl, q0, q1, q2, q3);  // (W0-W2)@X0
  __syncthreads();
  lap_step(U.ch.C0h, U.ch.Adj, -C1, w, ml, kq, NMh, NMl, U.ch.C1h);
  __syncthreads();
  yacc_k64(wr + 64, nullptr, w, ml, kq, NMh, NMl, q0, q1, q2, q3);  // W1@X1
  __syncthreads();
  lap_step(U.ch.C1h, U.ch.Adj, -2.0f * C1, w, ml, kq, NMh, NMl, nullptr);
  __syncthreads();
  yacc_k64(wr + 128, nullptr, w, ml, kq, NMh, NMl, q0, q1, q2, q3);  // W2@Z2
  float4 bb = *(const float4*)(bias + c0);
  y0 = addb(q0, bb); y1 = addb(q1, bb); y2 = addb(q2, bb); y3 = addb(q3, bb);
}

__device__ __forceinline__ void stats_round(
    int L, f32x4 ya0, f32x4 ya1, f32x4 ya2, f32x4 ya3, f32x4 yb0, f32x4 yb1,
    f32x4 yb2, f32x4 yb3, float* part, float* gstats, unsigned* bar,
    float* sStats, float* sRed, int blk, int t, int ml, int c0) {
  f32x4 a[4] = {ya0, ya1, ya2, ya3};
  f32x4 b[4] = {yb0, yb1, yb2, yb3};
  float s1[4] = {0.f, 0.f, 0.f, 0.f}, s2[4] = {0.f, 0.f, 0.f, 0.f};
#pragma unroll
  for (int nt = 0; nt < 4; nt++) {
#pragma unroll
    for (int i = 0; i < 4; i++) {
      float x = a[nt][i], y = b[nt][i];
      s1[i] += x + y;
      s2[i] += x * x + y * y;
    }
  }
#pragma unroll
  for (int i = 0; i < 4; i++) {
#pragma unroll
    for (int off = 1; off < 16; off <<= 1) {
      s1[i] += __shfl_xor(s1[i], off, 64);
      s2[i] += __shfl_xor(s2[i], off, 64);
    }
  }
  if (ml == 0) {
    float* prow = part + (size_t)blk * 128;
#pragma unroll
    for (int i = 0; i < 4; i++) {
      cstore(prow + c0 + i, s1[i]);
      cstore(prow + 64 + c0 + i, s2[i]);
    }
  }
  gbarrier(bar, L * 2, blk);
  if (blk < 8) {
    int cc = t & 15, rg = t >> 4;
    const float* pp = part + (size_t)(rg * 32) * 128 + blk * 16 + cc;
    float acc = 0.f;
#pragma unroll 8
    for (int r = 0; r < 32; r++) acc += cload(pp + (size_t)r * 128);
    sRed[t] = acc;
    __syncthreads();
    if (t < 16) {
      float s = 0.f;
#pragma unroll
      for (int k = 0; k < 16; k++) s += sRed[k * 16 + t];
      cstore(gstats + L * 128 + blk * 16 + t, s);
    }
  }
  gbarrier(bar, L * 2 + 1, blk);
  if (t < 128) sStats[t] = cload(gstats + L * 128 + t);
  __syncthreads();
}

__device__ __forceinline__ void pool_graph(const float* __restrict__ bn3g,
                                           const float* __restrict__ bn3b,
                                           float* __restrict__ out, int g,
                                           f32x4 y0, f32x4 y1, f32x4 y2,
                                           f32x4 y3, const float* sStats,
                                           int ml, int c0) {
  float sc[4], sh[4];
  bn_coeffs(sStats, bn3g, bn3b, c0, sc, sh);
  f32x4 yy[4] = {y0, y1, y2, y3};
  float vs[4] = {0.f, 0.f, 0.f, 0.f};
#pragma unroll
  for (int nt = 0; nt < 4; nt++)
#pragma unroll
    for (int i = 0; i < 4; i++)
      vs[i] += fmaxf(fmaf(sc[i], yy[nt][i], sh[i]), 0.f);
#pragma unroll
  for (int i = 0; i < 4; i++)
#pragma unroll
    for (int off = 1; off < 16; off <<= 1) vs[i] += __shfl_xor(vs[i], off, 64);
  if (ml == 0) {
    const float r64 = 1.0f / 64.0f;
    *(float4*)(out + (size_t)g * 64 + c0) =
        make_float4(vs[0] * r64, vs[1] * r64, vs[2] * r64, vs[3] * r64);
  }
}

// ---------------------------------------------------------------------------
__global__ __launch_bounds__(256, 3) void k_fused(
    const float* __restrict__ feat, const int* __restrict__ src,
    const float* __restrict__ c1w, const float* __restrict__ c1b,
    const float* __restrict__ bn1g, const float* __restrict__ bn1b,
    const float* __restrict__ e1tw, const float* __restrict__ e1tb,
    const float* __restrict__ e1pw, const float* __restrict__ e1pb,
    const float* __restrict__ bne1g, const float* __restrict__ bne1b,
    const float* __restrict__ c2w, const float* __restrict__ c2b,
    const float* __restrict__ bn2g, const float* __restrict__ bn2b,
    const float* __restrict__ e2tw, const float* __restrict__ e2tb,
    const float* __restrict__ e2pw, const float* __restrict__ e2pb,
    const float* __restrict__ bne2g, const float* __restrict__ bne2b,
    const float* __restrict__ c3w, const float* __restrict__ c3b,
    const float* __restrict__ bn3g, const float* __restrict__ bn3b,
    float* __restrict__ out, float* __restrict__ part,
    float* __restrict__ gstats, unsigned* __restrict__ bar) {
  __shared__ __align__(16) u16 NMh[4096];
  __shared__ __align__(16) u16 NMl[4096];
  __shared__ __align__(16) USh U;
  __shared__ float sStats[128];
  __shared__ float sRed[256];

  const int t = threadIdx.x, blk = blockIdx.x;
  const int lane = t & 63;
  const int w = __builtin_amdgcn_readfirstlane(t >> 6);
  const int ml = lane & 15, kq = lane >> 4;
  const int c0 = w * 16 + kq * 4;

  // persistent activations: 8 individually named f32x4 — VGPR-resident.
  f32x4 ya0, ya1, ya2, ya3, yb0, yb1, yb2, yb3;

  cheb1_graph(feat, src, c1w, c1b, blk * 2, ya0, ya1, ya2, ya3, NMh, NMl, U, t, lane, w, ml, kq, c0);
  cheb1_graph(feat, src, c1w, c1b, blk * 2 + 1, yb0, yb1, yb2, yb3, NMh, NMl, U, t, lane, w, ml, kq, c0);
  stats_round(0, ya0, ya1, ya2, ya3, yb0, yb1, yb2, yb3, part, gstats, bar, sStats, sRed, blk, t, ml, c0);

  econv_graph(src, bn1g, bn1b, e1tw, e1tb, e1pw, e1pb, blk * 2, ya0, ya1, ya2, ya3, NMh, NMl, U, sStats, t, w, ml, kq, c0);
  econv_graph(src, bn1g, bn1b, e1tw, e1tb, e1pw, e1pb, blk * 2 + 1, yb0, yb1, yb2, yb3, NMh, NMl, U, sStats, t, w, ml, kq, c0);
  stats_round(1, ya0, ya1, ya2, ya3, yb0, yb1, yb2, yb3, part, gstats, bar, sStats, sRed, blk, t, ml, c0);

  cheb64_graph(src, bne1g, bne1b, c2w, c2b, blk * 2, ya0, ya1, ya2, ya3, NMh, NMl, U, sStats, lane, w, ml, kq, c0);
  cheb64_graph(src, bne1g, bne1b, c2w, c2b, blk * 2 + 1, yb0, yb1, yb2, yb3, NMh, NMl, U, sStats, lane, w, ml, kq, c0);
  stats_round(2, ya0, ya1, ya2, ya3, yb0, yb1, yb2, yb3, part, gstats, bar, sStats, sRed, blk, t, ml, c0);

  econv_graph(src, bn2g, bn2b, e2tw, e2tb, e2pw, e2pb, blk * 2, ya0, ya1, ya2, ya3, NMh, NMl, U, sStats, t, w, ml, kq, c0);
  econv_graph(src, bn2g, bn2b, e2tw, e2tb, e2pw, e2pb, blk * 2 + 1, yb0, yb1, yb2, yb3, NMh, NMl, U, sStats, t, w, ml, kq, c0);
  stats_round(3, ya0, ya1, ya2, ya3, yb0, yb1, yb2, yb3, part, gstats, bar, sStats, sRed, blk, t, ml, c0);

  cheb64_graph(src, bne2g, bne2b, c3w, c3b, blk * 2, ya0, ya1, ya2, ya3, NMh, NMl, U, sStats, lane, w, ml, kq, c0);
  cheb64_graph(src, bne2g, bne2b, c3w, c3b, blk * 2 + 1, yb0, yb1, yb2, yb3, NMh, NMl, U, sStats, lane, w, ml, kq, c0);
  stats_round(4, ya0, ya1, ya2, ya3, yb0, yb1, yb2, yb3, part, gstats, bar, sStats, sRed, blk, t, ml, c0);

  pool_graph(bn3g, bn3b, out, blk * 2, ya0, ya1, ya2, ya3, sStats, ml, c0);
  pool_graph(bn3g, bn3b, out, blk * 2 + 1, yb0, yb1, yb2, yb3, sStats, ml, c0);
}

// ---------------------------------------------------------------------------
extern "C" void kernel_launch(void* const* d_in, const int* in_sizes, int n_in,
                              void* d_out, int out_size, void* d_ws,
                              size_t ws_size, hipStream_t stream) {
  const float* feat = (const float*)d_in[0];
  const int* src = (const int*)d_in[1];
  const float* cheb1_w = (const float*)d_in[4];
  const float* cheb1_b = (const float*)d_in[5];
  const float* bn1_g = (const float*)d_in[6];
  const float* bn1_b = (const float*)d_in[7];
  const float* e1_tw = (const float*)d_in[8];
  const float* e1_tb = (const float*)d_in[9];
  const float* e1_pw = (const float*)d_in[10];
  const float* e1_pb = (const float*)d_in[11];
  const float* bne1_g = (const float*)d_in[12];
  const float* bne1_b = (const float*)d_in[13];
  const float* cheb2_w = (const float*)d_in[14];
  const float* cheb2_b = (const float*)d_in[15];
  const float* bn2_g = (const float*)d_in[16];
  const float* bn2_b = (const float*)d_in[17];
  const float* e2_tw = (const float*)d_in[18];
  const float* e2_tb = (const float*)d_in[19];
  const float* e2_pw = (const float*)d_in[20];
  const float* e2_pb = (const float*)d_in[21];
  const float* bne2_g = (const float*)d_in[22];
  const float* bne2_b = (const float*)d_in[23];
  const float* cheb3_w = (const float*)d_in[24];
  const float* cheb3_b = (const float*)d_in[25];
  const float* bn3_g = (const float*)d_in[26];
  const float* bn3_b = (const float*)d_in[27];

  float* part = (float*)d_ws;                       // 512 x 128
  float* gstats = part + 512 * 128;                 // 5 x 128
  unsigned* bar = (unsigned*)(gstats + 5 * 128);    // 10 slots x 640 B

  hipMemsetAsync(bar, 0, 8192, stream);

  k_fused<<<512, 256, 0, stream>>>(
      feat, src, cheb1_w, cheb1_b, bn1_g, bn1_b, e1_tw, e1_tb, e1_pw, e1_pb,
      bne1_g, bne1_b, cheb2_w, cheb2_b, bn2_g, bn2_b, e2_tw, e2_tb, e2_pw,
      e2_pb, bne2_g, bne2_b, cheb3_w, cheb3_b, bn3_g, bn3_b, (float*)d_out,
      part, gstats, bar);
}